// Round 2
// baseline (11571.207 us; speedup 1.0000x reference)
//
#include <hip/hip_runtime.h>
#include <hip/hip_bf16.h>

// ---------------- constants ----------------
#define NTOK   6000
#define INDIM  1536
#define DIM    1024
#define NPL    6144      // padded seq for nystrom
#define PAD    59        // front pad (6144 - 6085)
#define NH     6085      // rows of h (cls + 6084)
#define HEADS  8
#define DHEAD  128
#define LMK    512
#define LSUB   12        // tokens per landmark
#define HW     78        // ppeg spatial
#define QSCALE 0.08838834764831845f  // 1/sqrt(128)

// ---------------- ws layout (float offsets), total ~49.3M floats = 197 MB ----------------
#define OFF_H    0LL                       // 6144*1024
#define OFF_LNXO 6291456LL                 // 6144*1024 (LNX, later aliased as O)
#define OFF_QKV  12582912LL                // 6144*3072 (also EO, PPEG F/F2)
#define OFF_S    31457280LL                // 512*6144 per-head scores
#define OFF_QL   34603008LL                // 8*512*128
#define OFF_KL   35127296LL
#define OFF_A2   35651584LL                // 8*512*512
#define OFF_Z    37748736LL
#define OFF_Z2   39845888LL
#define OFF_XZ   41943040LL
#define OFF_T1   44040192LL
#define OFF_T2   46137344LL
#define OFF_BV   48234496LL                // 8*512*128
#define OFF_ZB   48758784LL
#define OFF_COLS 49283072LL                // 4096
#define OFF_ROWS 49287168LL                // 4096
#define OFF_SCAL 49291264LL                // 16

// ---------------- reductions (blockDim.x == 256) ----------------
__device__ __forceinline__ float blk_sum(float v) {
    __shared__ float sb[4];
    #pragma unroll
    for (int o = 32; o > 0; o >>= 1) v += __shfl_down(v, o);
    int lane = threadIdx.x & 63, w = threadIdx.x >> 6;
    __syncthreads();
    if (lane == 0) sb[w] = v;
    __syncthreads();
    return sb[0] + sb[1] + sb[2] + sb[3];
}
__device__ __forceinline__ float blk_max(float v) {
    __shared__ float sb[4];
    #pragma unroll
    for (int o = 32; o > 0; o >>= 1) v = fmaxf(v, __shfl_down(v, o));
    int lane = threadIdx.x & 63, w = threadIdx.x >> 6;
    __syncthreads();
    if (lane == 0) sb[w] = v;
    __syncthreads();
    return fmaxf(fmaxf(sb[0], sb[1]), fmaxf(sb[2], sb[3]));
}

// ---------------- GEMM: C = A(M,K) @ B(N,K)^T, batched over z ----------------
// EPI: 0 plain store, 1 qkv (scale cols<1024), 3 C += acc + bias (proj residual)
template<int EPI>
__global__ __launch_bounds__(256)
void gemm_bt(const float* __restrict__ A, int lda, long long sA,
             const float* __restrict__ B, int ldb, long long sB,
             float* __restrict__ C, int ldc, long long sC,
             int M, int N, int K, const float* __restrict__ bias)
{
    A += blockIdx.z * sA; B += blockIdx.z * sB; C += blockIdx.z * sC;
    __shared__ float As[16][68];
    __shared__ float Bs[16][68];
    const int t = threadIdx.x;
    const int tx = t & 15, ty = t >> 4;
    const int row0 = blockIdx.y * 64, col0 = blockIdx.x * 64;
    const int lr = t >> 2;
    const int lk = (t & 3) << 2;
    const int arow = row0 + lr, brow = col0 + lr;
    float acc[4][4] = {{0.f,0.f,0.f,0.f},{0.f,0.f,0.f,0.f},{0.f,0.f,0.f,0.f},{0.f,0.f,0.f,0.f}};
    for (int kt = 0; kt < K; kt += 16) {
        float4 av = make_float4(0.f,0.f,0.f,0.f), bv = make_float4(0.f,0.f,0.f,0.f);
        if (arow < M) av = *(const float4*)(A + (long long)arow * lda + kt + lk);
        if (brow < N) bv = *(const float4*)(B + (long long)brow * ldb + kt + lk);
        As[lk+0][lr] = av.x; As[lk+1][lr] = av.y; As[lk+2][lr] = av.z; As[lk+3][lr] = av.w;
        Bs[lk+0][lr] = bv.x; Bs[lk+1][lr] = bv.y; Bs[lk+2][lr] = bv.z; Bs[lk+3][lr] = bv.w;
        __syncthreads();
        #pragma unroll
        for (int k = 0; k < 16; k++) {
            float aa[4], bb[4];
            *(float4*)aa = *(const float4*)&As[k][ty << 2];
            *(float4*)bb = *(const float4*)&Bs[k][tx << 2];
            #pragma unroll
            for (int i = 0; i < 4; i++)
                #pragma unroll
                for (int j = 0; j < 4; j++)
                    acc[i][j] = fmaf(aa[i], bb[j], acc[i][j]);
        }
        __syncthreads();
    }
    #pragma unroll
    for (int i = 0; i < 4; i++) {
        int r = row0 + (ty << 2) + i;
        if (r >= M) continue;
        #pragma unroll
        for (int j = 0; j < 4; j++) {
            int c = col0 + (tx << 2) + j;
            if (c >= N) continue;
            float v = acc[i][j];
            long long idx = (long long)r * ldc + c;
            if (EPI == 1)      C[idx] = (c < 1024) ? v * QSCALE : v;
            else if (EPI == 3) C[idx] += v + bias[c];
            else               C[idx] = v;
        }
    }
}

// ---------------- GEMM: C = alpha * A(M,K) @ (cdiag*I + sgn*B(K,N)), batched ----------------
// Requires M%64==0, N%64==0, K%16==0 (true for every use here).
__global__ __launch_bounds__(256)
void gemm_nn(const float* __restrict__ A, int lda, long long sA,
             const float* __restrict__ B, int ldb, long long sB,
             float* __restrict__ C, int ldc, long long sC,
             int M, int N, int K, float alpha, float cdiag, float sgn)
{
    A += blockIdx.z * sA; B += blockIdx.z * sB; C += blockIdx.z * sC;
    __shared__ float As[16][68];
    __shared__ float Bs[16][68];
    const int t = threadIdx.x;
    const int tx = t & 15, ty = t >> 4;
    const int row0 = blockIdx.y * 64, col0 = blockIdx.x * 64;
    const int lr = t >> 2, lk = (t & 3) << 2;
    const int bk = t >> 4, bn = (t & 15) << 2;
    float acc[4][4] = {{0.f,0.f,0.f,0.f},{0.f,0.f,0.f,0.f},{0.f,0.f,0.f,0.f},{0.f,0.f,0.f,0.f}};
    for (int kt = 0; kt < K; kt += 16) {
        float4 av = *(const float4*)(A + (long long)(row0 + lr) * lda + kt + lk);
        As[lk+0][lr] = av.x; As[lk+1][lr] = av.y; As[lk+2][lr] = av.z; As[lk+3][lr] = av.w;
        float4 bvv = *(const float4*)(B + (long long)(kt + bk) * ldb + col0 + bn);
        int gk = kt + bk, gn = col0 + bn;
        Bs[bk][bn+0] = sgn * bvv.x + ((gk == gn+0) ? cdiag : 0.f);
        Bs[bk][bn+1] = sgn * bvv.y + ((gk == gn+1) ? cdiag : 0.f);
        Bs[bk][bn+2] = sgn * bvv.z + ((gk == gn+2) ? cdiag : 0.f);
        Bs[bk][bn+3] = sgn * bvv.w + ((gk == gn+3) ? cdiag : 0.f);
        __syncthreads();
        #pragma unroll
        for (int k = 0; k < 16; k++) {
            float aa[4], bb[4];
            *(float4*)aa = *(const float4*)&As[k][ty << 2];
            *(float4*)bb = *(const float4*)&Bs[k][tx << 2];
            #pragma unroll
            for (int i = 0; i < 4; i++)
                #pragma unroll
                for (int j = 0; j < 4; j++)
                    acc[i][j] = fmaf(aa[i], bb[j], acc[i][j]);
        }
        __syncthreads();
    }
    #pragma unroll
    for (int i = 0; i < 4; i++) {
        int r = row0 + (ty << 2) + i;
        #pragma unroll
        for (int j = 0; j < 4; j++) {
            int c = col0 + (tx << 2) + j;
            C[(long long)r * ldc + c] = alpha * acc[i][j];
        }
    }
}

// ---------------- softmax over rows (W = NIT*256) ----------------
template<int NIT>
__global__ __launch_bounds__(256)
void softmax_rows(float* __restrict__ X, int W)
{
    long long row = blockIdx.x;
    float* x = X + row * W;
    float r[NIT];
    float m = -1e30f;
    #pragma unroll
    for (int i = 0; i < NIT; i++) { r[i] = x[threadIdx.x + i * 256]; m = fmaxf(m, r[i]); }
    m = blk_max(m);
    float s = 0.f;
    #pragma unroll
    for (int i = 0; i < NIT; i++) { r[i] = __expf(r[i] - m); s += r[i]; }
    s = blk_sum(s);
    float inv = 1.f / s;
    #pragma unroll
    for (int i = 0; i < NIT; i++) x[threadIdx.x + i * 256] = r[i] * inv;
}

// ---------------- LN + front-pad into X (6144 rows) ----------------
__global__ __launch_bounds__(256)
void ln_pad(const float* __restrict__ H, const float* __restrict__ g,
            const float* __restrict__ b, float* __restrict__ X)
{
    int row = blockIdx.x, t = threadIdx.x;
    float* o = X + (long long)row * DIM;
    if (row < PAD) {
        #pragma unroll
        for (int i = 0; i < 4; i++) o[t + i * 256] = 0.f;
        return;
    }
    const float* x = H + (long long)(row - PAD) * DIM;
    float r[4]; float s = 0.f;
    #pragma unroll
    for (int i = 0; i < 4; i++) { r[i] = x[t + i * 256]; s += r[i]; }
    float mu = blk_sum(s) * (1.f / DIM);
    float v = 0.f;
    #pragma unroll
    for (int i = 0; i < 4; i++) { float d = r[i] - mu; v += d * d; }
    float var = blk_sum(v) * (1.f / DIM);
    float rs = rsqrtf(var + 1e-5f);
    #pragma unroll
    for (int i = 0; i < 4; i++) { int c = t + i * 256; o[c] = (r[i] - mu) * rs * g[c] + b[c]; }
}

// ---------------- landmarks: mean over 12 consecutive tokens ----------------
__global__ __launch_bounds__(128)
void landmarks(const float* __restrict__ QKV, float* __restrict__ QL, float* __restrict__ KL)
{
    int L = blockIdx.x, h = blockIdx.y, d = threadIdx.x;
    float sq = 0.f, sk = 0.f;
    #pragma unroll
    for (int j = 0; j < LSUB; j++) {
        const float* p = QKV + (long long)(L * LSUB + j) * 3072 + h * DHEAD + d;
        sq += p[0];
        sk += p[1024];
    }
    QL[(long long)(h * LMK + L) * DHEAD + d] = sq * (1.f / LSUB);
    KL[(long long)(h * LMK + L) * DHEAD + d] = sk * (1.f / LSUB);
}

// ---------------- a2 row/col sums, then scalar 1/(maxrow*maxcol) ----------------
__global__ __launch_bounds__(256)
void a2_sums(const float* __restrict__ A2, float* __restrict__ cols, float* __restrict__ rows)
{
    int h = blockIdx.x, t = threadIdx.x;
    const float* a = A2 + (long long)h * LMK * LMK;
    for (int j = t; j < LMK; j += 256) {
        float s = 0.f;
        for (int i = 0; i < LMK; i++) s += fabsf(a[(long long)i * LMK + j]);
        cols[h * LMK + j] = s;
    }
    for (int r = t; r < LMK; r += 256) {
        float s = 0.f;
        const float* p = a + (long long)r * LMK;
        for (int j = 0; j < LMK; j++) s += fabsf(p[j]);
        rows[h * LMK + r] = s;
    }
}
__global__ __launch_bounds__(256)
void a2_scal(const float* __restrict__ cols, const float* __restrict__ rows, float* __restrict__ scal)
{
    float mc = -1e30f, mr = -1e30f;
    for (int i = threadIdx.x; i < HEADS * LMK; i += 256) {
        mc = fmaxf(mc, cols[i]); mr = fmaxf(mr, rows[i]);
    }
    mc = blk_max(mc); mr = blk_max(mr);
    if (threadIdx.x == 0) scal[0] = 1.f / (mc * mr);
}

// ---------------- z0 = a2^T * scal ----------------
__global__ void z0_t(const float* __restrict__ A2, float* __restrict__ Z, const float* __restrict__ scal)
{
    __shared__ float tile[32][33];
    int h = blockIdx.z;
    const float* a = A2 + (long long)h * LMK * LMK;
    float* z = Z + (long long)h * LMK * LMK;
    float s = scal[0];
    int x0 = blockIdx.x * 32, y0 = blockIdx.y * 32;
    int tx = threadIdx.x, ty = threadIdx.y;
    for (int yy = ty; yy < 32; yy += 8) tile[yy][tx] = a[(long long)(y0 + yy) * LMK + x0 + tx];
    __syncthreads();
    for (int yy = ty; yy < 32; yy += 8) z[(long long)(x0 + yy) * LMK + y0 + tx] = tile[tx][yy] * s;
}

// ---------------- MoE ----------------
__global__ __launch_bounds__(256)
void moe_combine(const float* __restrict__ X, const float* __restrict__ wg,
                 const float* __restrict__ EO, const float* __restrict__ eb,
                 float* __restrict__ H)
{
    int i = blockIdx.x, t = threadIdx.x;
    const float* x = X + (long long)i * INDIM;
    float g0 = 0.f, g1 = 0.f, g2 = 0.f;
    for (int f = t; f < INDIM; f += 256) {
        float xv = x[f];
        const float* w = wg + f * 3;
        g0 += xv * w[0]; g1 += xv * w[1]; g2 += xv * w[2];
    }
    g0 = blk_sum(g0); g1 = blk_sum(g1); g2 = blk_sum(g2);
    float m = fmaxf(g0, fmaxf(g1, g2));
    float e0 = __expf(g0 - m), e1 = __expf(g1 - m), e2 = __expf(g2 - m);
    float inv = 1.f / (e0 + e1 + e2);
    e0 *= inv; e1 *= inv; e2 *= inv;
    const float* eo = EO + (long long)i * 3072;
    for (int o = t; o < DIM; o += 256) {
        float v0 = fmaxf(eo[o]          + eb[o],          0.f);
        float v1 = fmaxf(eo[1024 + o]   + eb[1024 + o],   0.f);
        float v2 = fmaxf(eo[2048 + o]   + eb[2048 + o],   0.f);
        float r = e0 * v0 + e1 * v1 + e2 * v2;
        H[(long long)(1 + i) * DIM + o] = r;
        if (i < 84) H[(long long)(6001 + i) * DIM + o] = r;  // wrap rows
    }
}

__global__ void cls_copy(const float* __restrict__ c, float* __restrict__ H)
{
    for (int i = threadIdx.x; i < DIM; i += 256) H[i] = c[i];
}

// ---------------- depthwise 33-tap res conv on V, added to O ----------------
__global__ __launch_bounds__(256)
void resconv(const float* __restrict__ QKV, const float* __restrict__ rw, float* __restrict__ O)
{
    long long idx = (long long)blockIdx.x * 256 + threadIdx.x;  // over NPL*DIM
    int c = (int)(idx & 1023);
    long long i = idx >> 10;
    int h = c >> 7;
    float acc = 0.f;
    #pragma unroll
    for (int t = 0; t < 33; t++) {
        long long r = i + t - 16;
        if (r >= 0 && r < NPL) acc += rw[h * 33 + t] * QKV[r * 3072 + 2048 + c];
    }
    O[idx] += acc;
}

// ---------------- PPEG ----------------
__global__ void h2f(const float* __restrict__ H, float* __restrict__ F)
{
    __shared__ float tile[32][33];
    int p0 = blockIdx.x * 32, c0 = blockIdx.y * 32;
    int tx = threadIdx.x, ty = threadIdx.y;
    for (int yy = ty; yy < 32; yy += 8) {
        int p = p0 + yy;
        if (p < HW * HW) tile[yy][tx] = H[(long long)(1 + p) * DIM + c0 + tx];
    }
    __syncthreads();
    for (int yy = ty; yy < 32; yy += 8) {
        int p = p0 + tx, c = c0 + yy;
        if (p < HW * HW) F[(long long)c * (HW * HW) + p] = tile[tx][yy];
    }
}
__global__ void f2h(const float* __restrict__ F2, float* __restrict__ H)
{
    __shared__ float tile[32][33];
    int c0 = blockIdx.x * 32, p0 = blockIdx.y * 32;
    int tx = threadIdx.x, ty = threadIdx.y;
    for (int yy = ty; yy < 32; yy += 8) {
        int p = p0 + tx;
        if (p < HW * HW) tile[yy][tx] = F2[(long long)(c0 + yy) * (HW * HW) + p];
    }
    __syncthreads();
    for (int yy = ty; yy < 32; yy += 8) {
        int p = p0 + yy;
        if (p < HW * HW) H[(long long)(1 + p) * DIM + c0 + tx] = tile[tx][yy];
    }
}
__global__ __launch_bounds__(256)
void ppeg_conv(const float* __restrict__ F,
               const float* __restrict__ w7, const float* __restrict__ b7,
               const float* __restrict__ w5, const float* __restrict__ b5,
               const float* __restrict__ w3, const float* __restrict__ b3,
               float* __restrict__ F2)
{
    int c = blockIdx.x, t = threadIdx.x;
    __shared__ float plane[HW * HW];
    __shared__ float ws7[49], ws5[25], ws3[9];
    for (int p = t; p < HW * HW; p += 256) plane[p] = F[(long long)c * (HW * HW) + p];
    if (t < 49) ws7[t] = w7[(long long)c * 49 + t];
    if (t < 25) ws5[t] = w5[(long long)c * 25 + t];
    if (t < 9)  ws3[t] = w3[(long long)c * 9 + t];
    __syncthreads();
    float bsum = b7[c] + b5[c] + b3[c];
    for (int p = t; p < HW * HW; p += 256) {
        int y = p / HW, x = p - y * HW;
        float acc = plane[p] + bsum;
        for (int ky = -3; ky <= 3; ky++) {
            int yy = y + ky; if ((unsigned)yy >= (unsigned)HW) continue;
            for (int kx = -3; kx <= 3; kx++) {
                int xx = x + kx; if ((unsigned)xx >= (unsigned)HW) continue;
                acc += ws7[(ky + 3) * 7 + (kx + 3)] * plane[yy * HW + xx];
            }
        }
        for (int ky = -2; ky <= 2; ky++) {
            int yy = y + ky; if ((unsigned)yy >= (unsigned)HW) continue;
            for (int kx = -2; kx <= 2; kx++) {
                int xx = x + kx; if ((unsigned)xx >= (unsigned)HW) continue;
                acc += ws5[(ky + 2) * 5 + (kx + 2)] * plane[yy * HW + xx];
            }
        }
        for (int ky = -1; ky <= 1; ky++) {
            int yy = y + ky; if ((unsigned)yy >= (unsigned)HW) continue;
            for (int kx = -1; kx <= 1; kx++) {
                int xx = x + kx; if ((unsigned)xx >= (unsigned)HW) continue;
                acc += ws3[(ky + 1) * 3 + (kx + 1)] * plane[yy * HW + xx];
            }
        }
        F2[(long long)c * (HW * HW) + p] = acc;
    }
}

// ---------------- final head: LN(row0) -> fc2 -> softmax -> argmax ----------------
__global__ __launch_bounds__(256)
void head_k(const float* __restrict__ H, const float* __restrict__ g, const float* __restrict__ b,
            const float* __restrict__ fw, const float* __restrict__ fb, float* __restrict__ out)
{
    int t = threadIdx.x;
    float r[4]; float s = 0.f;
    #pragma unroll
    for (int i = 0; i < 4; i++) { r[i] = H[t + i * 256]; s += r[i]; }
    float mu = blk_sum(s) * (1.f / DIM);
    float v = 0.f;
    #pragma unroll
    for (int i = 0; i < 4; i++) { float d = r[i] - mu; v += d * d; }
    float var = blk_sum(v) * (1.f / DIM);
    float rs = rsqrtf(var + 1e-5f);
    float d0 = 0.f, d1 = 0.f;
    #pragma unroll
    for (int i = 0; i < 4; i++) {
        int c = t + i * 256;
        float hv = (r[i] - mu) * rs * g[c] + b[c];
        d0 += hv * fw[c];
        d1 += hv * fw[DIM + c];
    }
    d0 = blk_sum(d0); d1 = blk_sum(d1);
    if (t == 0) {
        float l0 = d0 + fb[0], l1 = d1 + fb[1];
        float m = fmaxf(l0, l1);
        float e0 = __expf(l0 - m), e1 = __expf(l1 - m);
        float inv = 1.f / (e0 + e1);
        out[0] = l0; out[1] = l1;
        out[2] = e0 * inv; out[3] = e1 * inv;
        out[4] = (l1 > l0) ? 1.0f : 0.0f;
    }
}

// ---------------- host ----------------
extern "C" void kernel_launch(void* const* d_in, const int* in_sizes, int n_in,
                              void* d_out, int out_size, void* d_ws, size_t ws_size,
                              hipStream_t stream)
{
    const float* data     = (const float*)d_in[0];
    const float* w_gate   = (const float*)d_in[1];
    const float* expert_w = (const float*)d_in[2];
    const float* expert_b = (const float*)d_in[3];
    const float* cls_tok  = (const float*)d_in[4];
    const float* ln_g[2]  = {(const float*)d_in[5],  (const float*)d_in[11]};
    const float* ln_b[2]  = {(const float*)d_in[6],  (const float*)d_in[12]};
    const float* qkv_w[2] = {(const float*)d_in[7],  (const float*)d_in[13]};
    const float* out_w[2] = {(const float*)d_in[8],  (const float*)d_in[14]};
    const float* out_b[2] = {(const float*)d_in[9],  (const float*)d_in[15]};
    const float* res_w[2] = {(const float*)d_in[10], (const float*)d_in[16]};
    const float* pw7 = (const float*)d_in[17]; const float* pb7 = (const float*)d_in[18];
    const float* pw5 = (const float*)d_in[19]; const float* pb5 = (const float*)d_in[20];
    const float* pw3 = (const float*)d_in[21]; const float* pb3 = (const float*)d_in[22];
    const float* nf_g = (const float*)d_in[23]; const float* nf_b = (const float*)d_in[24];
    const float* fc2w = (const float*)d_in[25]; const float* fc2b = (const float*)d_in[26];

    float* ws  = (float*)d_ws;
    float* H   = ws + OFF_H;
    float* LNX = ws + OFF_LNXO;
    float* O   = ws + OFF_LNXO;   // alias: O written only after LNX is dead
    float* QKV = ws + OFF_QKV;    // also EO and PPEG planes
    float* S   = ws + OFF_S;      // per-head score buffer
    float* QL  = ws + OFF_QL;
    float* KL  = ws + OFF_KL;
    float* A2  = ws + OFF_A2;
    float* Z   = ws + OFF_Z;
    float* Z2  = ws + OFF_Z2;
    float* XZ  = ws + OFF_XZ;
    float* T1  = ws + OFF_T1;
    float* T2  = ws + OFF_T2;
    float* BV  = ws + OFF_BV;
    float* ZB  = ws + OFF_ZB;
    float* COLS = ws + OFF_COLS;
    float* ROWS = ws + OFF_ROWS;
    float* SCAL = ws + OFF_SCAL;

    // ---- MoE ----
    // EO = data @ expert_w_stacked^T  (6000 x 3072), staged in QKV region
    gemm_bt<0><<<dim3(48, 94, 1), 256, 0, stream>>>(data, INDIM, 0, expert_w, INDIM, 0,
                                                    QKV, 3072, 0, NTOK, 3072, INDIM, nullptr);
    moe_combine<<<NTOK, 256, 0, stream>>>(data, w_gate, QKV, expert_b, H);
    cls_copy<<<1, 256, 0, stream>>>(cls_tok, H);

    const long long HS = (long long)LMK * DHEAD;       // 65536
    const long long A2S = (long long)LMK * LMK;        // 262144

    for (int stage = 0; stage < 2; stage++) {
        // LN + pad
        ln_pad<<<NPL, 256, 0, stream>>>(H, ln_g[stage], ln_b[stage], LNX);
        // QKV = LNX @ qkv_w^T  (q scaled)
        gemm_bt<1><<<dim3(48, 96, 1), 256, 0, stream>>>(LNX, DIM, 0, qkv_w[stage], DIM, 0,
                                                        QKV, 3072, 0, NPL, 3072, DIM, nullptr);
        // landmarks
        landmarks<<<dim3(LMK, HEADS), 128, 0, stream>>>(QKV, QL, KL);
        // a2 = softmax(ql @ kl^T), batched over heads
        gemm_bt<0><<<dim3(8, 8, HEADS), 256, 0, stream>>>(QL, DHEAD, HS, KL, DHEAD, HS,
                                                          A2, LMK, A2S, LMK, LMK, DHEAD, nullptr);
        softmax_rows<2><<<HEADS * LMK, 256, 0, stream>>>(A2, LMK);
        // pinv init
        a2_sums<<<HEADS, 256, 0, stream>>>(A2, COLS, ROWS);
        a2_scal<<<1, 256, 0, stream>>>(COLS, ROWS, SCAL);
        z0_t<<<dim3(16, 16, HEADS), dim3(32, 8), 0, stream>>>(A2, Z, SCAL);
        // Newton-Schulz iterations (batched over heads)
        float* zin = Z; float* zout = Z2;
        for (int it = 0; it < 6; it++) {
            gemm_nn<<<dim3(8, 8, HEADS), 256, 0, stream>>>(A2, LMK, A2S, zin, LMK, A2S,
                                                           XZ, LMK, A2S, LMK, LMK, LMK, 1.f, 0.f, 1.f);
            gemm_nn<<<dim3(8, 8, HEADS), 256, 0, stream>>>(XZ, LMK, A2S, XZ, LMK, A2S,
                                                           T1, LMK, A2S, LMK, LMK, LMK, 1.f, 7.f, -1.f);
            gemm_nn<<<dim3(8, 8, HEADS), 256, 0, stream>>>(XZ, LMK, A2S, T1, LMK, A2S,
                                                           T2, LMK, A2S, LMK, LMK, LMK, 1.f, 15.f, -1.f);
            gemm_nn<<<dim3(8, 8, HEADS), 256, 0, stream>>>(zin, LMK, A2S, T2, LMK, A2S,
                                                           zout, LMK, A2S, LMK, LMK, LMK, 0.25f, 13.f, -1.f);
            float* tmp = zin; zin = zout; zout = tmp;
        }
        // a3 = softmax(ql @ k^T); bv = a3 @ v   (per head, shared S buffer)
        for (int h = 0; h < HEADS; h++) {
            gemm_bt<0><<<dim3(96, 8, 1), 256, 0, stream>>>(QL + h * HS, DHEAD, 0,
                                                           QKV + 1024 + h * DHEAD, 3072, 0,
                                                           S, NPL, 0, LMK, NPL, DHEAD, nullptr);
            softmax_rows<24><<<LMK, 256, 0, stream>>>(S, NPL);
            gemm_nn<<<dim3(2, 8, 1), 256, 0, stream>>>(S, NPL, 0, QKV + 2048 + h * DHEAD, 3072, 0,
                                                       BV + h * HS, DHEAD, 0, LMK, DHEAD, NPL, 1.f, 0.f, 1.f);
        }
        // zb = z_final @ bv (batched)
        gemm_nn<<<dim3(2, 8, HEADS), 256, 0, stream>>>(zin, LMK, A2S, BV, DHEAD, HS,
                                                       ZB, DHEAD, HS, LMK, DHEAD, LMK, 1.f, 0.f, 1.f);
        // a1 = softmax(q @ kl^T); O = a1 @ zb   (per head, shared S buffer)
        for (int h = 0; h < HEADS; h++) {
            gemm_bt<0><<<dim3(8, 96, 1), 256, 0, stream>>>(QKV + h * DHEAD, 3072, 0,
                                                           KL + h * HS, DHEAD, 0,
                                                           S, LMK, 0, NPL, LMK, DHEAD, nullptr);
            softmax_rows<2><<<NPL, 256, 0, stream>>>(S, LMK);
            gemm_nn<<<dim3(2, 96, 1), 256, 0, stream>>>(S, LMK, 0, ZB + h * HS, DHEAD, 0,
                                                        O + h * DHEAD, DIM, 0, NPL, DHEAD, LMK, 1.f, 0.f, 1.f);
        }
        // O += depthwise res conv of v
        resconv<<<(NPL * DIM) / 256, 256, 0, stream>>>(QKV, res_w[stage], O);
        // H += (O @ out_w^T + out_b), rows PAD.. map to H rows 0..
        gemm_bt<3><<<dim3(16, 96, 1), 256, 0, stream>>>(O + (long long)PAD * DIM, DIM, 0,
                                                        out_w[stage], DIM, 0, H, DIM, 0,
                                                        NH, DIM, DIM, out_b[stage]);
        // PPEG between the two nystrom stages (planes alias QKV region)
        if (stage == 0) {
            float* F  = QKV;                     // 1024 x 6084
            float* F2 = QKV + 6291456LL;
            h2f<<<dim3(191, 32), dim3(32, 8), 0, stream>>>(H, F);
            ppeg_conv<<<DIM, 256, 0, stream>>>(F, pw7, pb7, pw5, pb5, pw3, pb3, F2);
            f2h<<<dim3(32, 191), dim3(32, 8), 0, stream>>>(F2, H);
        }
    }

    head_k<<<1, 256, 0, stream>>>(H, nf_g, nf_b, fc2w, fc2b, (float*)d_out);
}

// Round 3
// 3092.649 us; speedup vs baseline: 3.7415x; 3.7415x over previous
//
#include <hip/hip_runtime.h>
#include <hip/hip_bf16.h>

// ---------------- constants ----------------
#define NTOK   6000
#define INDIM  1536
#define DIM    1024
#define NPL    6144
#define PAD    59
#define NH     6085
#define HEADS  8
#define DHEAD  128
#define LMK    512
#define LSUB   12
#define HW     78
#define QSCALE 0.08838834764831845f

// ---------------- ws layout (float-slot offsets), ~208 MB ----------------
#define OFF_H     0LL          // 6144*1024 f32
#define OFF_LNXO  6291456LL    // LNX bf16 (first half) / O f32 (full), 6144*1024 f32 slots
#define OFF_QKVB  12582912LL   // 6144*3072 bf16 = 9437184 slots; EO f32 + PPEG planes alias here
#define OFF_S     22020096LL   // 8*512*6144 bf16 = 12582912 slots
#define OFF_VT    34603008LL   // 8*128*6144 bf16 = 3145728 slots
#define OFF_QL    37748736LL   // 8*512*128 bf16 = 262144 slots
#define OFF_KL    38010880LL
#define OFF_A2    38273024LL   // 8*512*512 f32
#define OFF_Z     40370176LL
#define OFF_Z2    42467328LL
#define OFF_XZ    44564480LL
#define OFF_T1    46661632LL
#define OFF_T2    48758784LL
#define OFF_BV    50855936LL   // 8*512*128 f32
#define OFF_ZBT   51380224LL   // 8*128*512 f32
#define OFF_COLS  51904512LL
#define OFF_ROWS  51908608LL
#define OFF_SCAL  51912704LL

typedef __attribute__((ext_vector_type(8))) short s16x8;
typedef __attribute__((ext_vector_type(4))) float f32x4;

// ---------------- bf16 helpers ----------------
__device__ __forceinline__ ushort f2b(float f) {
    union { float f; unsigned u; } v; v.f = f;
    return (ushort)((v.u + 0x7FFF + ((v.u >> 16) & 1)) >> 16);
}
__device__ __forceinline__ float b2f(ushort h) {
    union { unsigned u; float f; } v; v.u = ((unsigned)h) << 16; return v.f;
}
__device__ __forceinline__ unsigned pk2(float a, float b) {
    return (unsigned)f2b(a) | ((unsigned)f2b(b) << 16);
}

// ---------------- reductions (blockDim.x == 256) ----------------
__device__ __forceinline__ float blk_sum(float v) {
    __shared__ float sb[4];
    #pragma unroll
    for (int o = 32; o > 0; o >>= 1) v += __shfl_down(v, o);
    int lane = threadIdx.x & 63, w = threadIdx.x >> 6;
    __syncthreads();
    if (lane == 0) sb[w] = v;
    __syncthreads();
    return sb[0] + sb[1] + sb[2] + sb[3];
}
__device__ __forceinline__ float blk_max(float v) {
    __shared__ float sb[4];
    #pragma unroll
    for (int o = 32; o > 0; o >>= 1) v = fmaxf(v, __shfl_down(v, o));
    int lane = threadIdx.x & 63, w = threadIdx.x >> 6;
    __syncthreads();
    if (lane == 0) sb[w] = v;
    __syncthreads();
    return fmaxf(fmaxf(sb[0], sb[1]), fmaxf(sb[2], sb[3]));
}

// ================= MFMA GEMM =================
// C = alpha * A(M,K) @ op(B), tile 128x128x32, 4 waves.
// NN=0: op(B) = B^T where B is N x K row-major (both A,B staged identically).
// NN=1: op(B) = cdiag*I + sgn*B where B is K x N row-major (transposed scalar staging).
// TA/TB: float (converted to bf16 in staging) or ushort (raw bf16 copy).
// EPI: 0 = f32 store (alpha applied); 1 = bf16 store, cols<1024 scaled by QSCALE;
//      2 = bf16 store; 3 = f32 C += acc + bias[c].
template<int EPI, int NN, typename TA, typename TB>
__global__ __launch_bounds__(256)
void mgemm(const TA* __restrict__ A, int lda, long long sA,
           const TB* __restrict__ B, int ldb, long long sB,
           void* __restrict__ Cp, int ldc, long long sC,
           int M, int K, const float* __restrict__ bias,
           float alpha, float cdiag, float sgn)
{
    __shared__ ushort As[128 * 40];
    __shared__ ushort Bs[128 * 40];
    const int t = threadIdx.x;
    const int row0 = blockIdx.y * 128, col0 = blockIdx.x * 128;
    A += blockIdx.z * sA; B += blockIdx.z * sB;
    const int sr  = t >> 1, skq = (t & 1) * 16;   // staging: row, k-seg
    const int nk  = t >> 3, nns = (t & 7) * 16;   // NN B staging: k, n-seg
    const int w   = t >> 6, lane = t & 63;
    const int wr  = (w >> 1) * 64, wc = (w & 1) * 64;
    const int fr  = lane & 15, fk = (lane >> 4) * 8;

    f32x4 acc[4][4];
    #pragma unroll
    for (int a = 0; a < 4; a++)
        #pragma unroll
        for (int b = 0; b < 4; b++)
            acc[a][b] = (f32x4){0.f, 0.f, 0.f, 0.f};

    for (int kt = 0; kt < K; kt += 32) {
        // ---- stage A (row-major M x K) ----
        {
            long long ar = row0 + sr;
            uint4 w0 = make_uint4(0,0,0,0), w1 = make_uint4(0,0,0,0);
            if (ar < M) {
                if constexpr (sizeof(TA) == 2) {
                    const ushort* p = (const ushort*)A + ar * (long long)lda + kt + skq;
                    w0 = *(const uint4*)p; w1 = *(const uint4*)(p + 8);
                } else {
                    const float* p = (const float*)A + ar * (long long)lda + kt + skq;
                    float4 f0 = *(const float4*)p,     f1 = *(const float4*)(p + 4);
                    float4 f2 = *(const float4*)(p + 8), f3 = *(const float4*)(p + 12);
                    w0.x = pk2(f0.x, f0.y); w0.y = pk2(f0.z, f0.w);
                    w0.z = pk2(f1.x, f1.y); w0.w = pk2(f1.z, f1.w);
                    w1.x = pk2(f2.x, f2.y); w1.y = pk2(f2.z, f2.w);
                    w1.z = pk2(f3.x, f3.y); w1.w = pk2(f3.z, f3.w);
                }
            }
            *(uint4*)&As[sr * 40 + skq]     = w0;
            *(uint4*)&As[sr * 40 + skq + 8] = w1;
        }
        // ---- stage B ----
        if constexpr (!NN) {
            long long br = col0 + sr;
            uint4 w0, w1;
            if constexpr (sizeof(TB) == 2) {
                const ushort* p = (const ushort*)B + br * (long long)ldb + kt + skq;
                w0 = *(const uint4*)p; w1 = *(const uint4*)(p + 8);
            } else {
                const float* p = (const float*)B + br * (long long)ldb + kt + skq;
                float4 f0 = *(const float4*)p,     f1 = *(const float4*)(p + 4);
                float4 f2 = *(const float4*)(p + 8), f3 = *(const float4*)(p + 12);
                w0.x = pk2(f0.x, f0.y); w0.y = pk2(f0.z, f0.w);
                w0.z = pk2(f1.x, f1.y); w0.w = pk2(f1.z, f1.w);
                w1.x = pk2(f2.x, f2.y); w1.y = pk2(f2.z, f2.w);
                w1.z = pk2(f3.x, f3.y); w1.w = pk2(f3.z, f3.w);
            }
            *(uint4*)&Bs[sr * 40 + skq]     = w0;
            *(uint4*)&Bs[sr * 40 + skq + 8] = w1;
        } else {
            int gk = kt + nk;
            const float* p = (const float*)B + (long long)gk * ldb + col0 + nns;
            float4 f0 = *(const float4*)p,     f1 = *(const float4*)(p + 4);
            float4 f2 = *(const float4*)(p + 8), f3 = *(const float4*)(p + 12);
            float vv[16] = {f0.x,f0.y,f0.z,f0.w, f1.x,f1.y,f1.z,f1.w,
                            f2.x,f2.y,f2.z,f2.w, f3.x,f3.y,f3.z,f3.w};
            #pragma unroll
            for (int i = 0; i < 16; i++) {
                int gn = col0 + nns + i;
                float v = sgn * vv[i] + (gk == gn ? cdiag : 0.f);
                Bs[(nns + i) * 40 + nk] = f2b(v);
            }
        }
        __syncthreads();
        // ---- MFMA ----
        s16x8 af[4], bf[4];
        #pragma unroll
        for (int a = 0; a < 4; a++) af[a] = *(const s16x8*)&As[(wr + a*16 + fr) * 40 + fk];
        #pragma unroll
        for (int b = 0; b < 4; b++) bf[b] = *(const s16x8*)&Bs[(wc + b*16 + fr) * 40 + fk];
        #pragma unroll
        for (int a = 0; a < 4; a++)
            #pragma unroll
            for (int b = 0; b < 4; b++)
                acc[a][b] = __builtin_amdgcn_mfma_f32_16x16x32_bf16(af[a], bf[b], acc[a][b], 0, 0, 0);
        __syncthreads();
    }

    // ---- epilogue ----
    const int er = row0 + wr + (lane >> 4) * 4;
    const int ec = col0 + wc + fr;
    #pragma unroll
    for (int a = 0; a < 4; a++) {
        #pragma unroll
        for (int j = 0; j < 4; j++) {
            int r = er + a * 16 + j;
            if (r >= M) continue;
            #pragma unroll
            for (int b = 0; b < 4; b++) {
                int c = ec + b * 16;
                float v = acc[a][b][j] * alpha;
                long long idx = blockIdx.z * sC + (long long)r * ldc + c;
                if constexpr (EPI == 0)      ((float*)Cp)[idx] = v;
                else if constexpr (EPI == 1) ((ushort*)Cp)[idx] = f2b(c < 1024 ? v * QSCALE : v);
                else if constexpr (EPI == 2) ((ushort*)Cp)[idx] = f2b(v);
                else                         ((float*)Cp)[idx] += v + bias[c];
            }
        }
    }
}

// ---------------- fp32 GEMM: C = alpha * A(M,K) @ (cdiag*I + sgn*B(K,N)) ----------------
// TSTORE=1: store transposed C[c*ldc + r]. Requires M%64==0, N%64==0, K%16==0.
template<int TSTORE>
__global__ __launch_bounds__(256)
void gemm_nn(const float* __restrict__ A, int lda, long long sA,
             const float* __restrict__ B, int ldb, long long sB,
             float* __restrict__ C, int ldc, long long sC,
             int M, int N, int K, float alpha, float cdiag, float sgn)
{
    A += blockIdx.z * sA; B += blockIdx.z * sB; C += blockIdx.z * sC;
    __shared__ float As[16][68];
    __shared__ float Bs[16][68];
    const int t = threadIdx.x;
    const int tx = t & 15, ty = t >> 4;
    const int row0 = blockIdx.y * 64, col0 = blockIdx.x * 64;
    const int lr = t >> 2, lk = (t & 3) << 2;
    const int bk = t >> 4, bn = (t & 15) << 2;
    float acc[4][4] = {{0.f,0.f,0.f,0.f},{0.f,0.f,0.f,0.f},{0.f,0.f,0.f,0.f},{0.f,0.f,0.f,0.f}};
    for (int kt = 0; kt < K; kt += 16) {
        float4 av = *(const float4*)(A + (long long)(row0 + lr) * lda + kt + lk);
        As[lk+0][lr] = av.x; As[lk+1][lr] = av.y; As[lk+2][lr] = av.z; As[lk+3][lr] = av.w;
        float4 bvv = *(const float4*)(B + (long long)(kt + bk) * ldb + col0 + bn);
        int gk = kt + bk, gn = col0 + bn;
        Bs[bk][bn+0] = sgn * bvv.x + ((gk == gn+0) ? cdiag : 0.f);
        Bs[bk][bn+1] = sgn * bvv.y + ((gk == gn+1) ? cdiag : 0.f);
        Bs[bk][bn+2] = sgn * bvv.z + ((gk == gn+2) ? cdiag : 0.f);
        Bs[bk][bn+3] = sgn * bvv.w + ((gk == gn+3) ? cdiag : 0.f);
        __syncthreads();
        #pragma unroll
        for (int k = 0; k < 16; k++) {
            float aa[4], bb[4];
            *(float4*)aa = *(const float4*)&As[k][ty << 2];
            *(float4*)bb = *(const float4*)&Bs[k][tx << 2];
            #pragma unroll
            for (int i = 0; i < 4; i++)
                #pragma unroll
                for (int j = 0; j < 4; j++)
                    acc[i][j] = fmaf(aa[i], bb[j], acc[i][j]);
        }
        __syncthreads();
    }
    #pragma unroll
    for (int i = 0; i < 4; i++) {
        int r = row0 + (ty << 2) + i;
        #pragma unroll
        for (int j = 0; j < 4; j++) {
            int c = col0 + (tx << 2) + j;
            if (TSTORE) C[(long long)c * ldc + r] = alpha * acc[i][j];
            else        C[(long long)r * ldc + c] = alpha * acc[i][j];
        }
    }
}

// ---------------- softmax fp32 rows (W = NIT*256) ----------------
template<int NIT>
__global__ __launch_bounds__(256)
void softmax_rows(float* __restrict__ X, int W)
{
    long long row = blockIdx.x;
    float* x = X + row * W;
    float r[NIT];
    float m = -1e30f;
    #pragma unroll
    for (int i = 0; i < NIT; i++) { r[i] = x[threadIdx.x + i * 256]; m = fmaxf(m, r[i]); }
    m = blk_max(m);
    float s = 0.f;
    #pragma unroll
    for (int i = 0; i < NIT; i++) { r[i] = __expf(r[i] - m); s += r[i]; }
    s = blk_sum(s);
    float inv = 1.f / s;
    #pragma unroll
    for (int i = 0; i < NIT; i++) x[threadIdx.x + i * 256] = r[i] * inv;
}

// ---------------- softmax bf16, W=6144 ----------------
__global__ __launch_bounds__(256)
void softmax_b6144(ushort* __restrict__ X)
{
    long long row = blockIdx.x;
    ushort* x = X + row * 6144;
    int t = threadIdx.x;
    float r[24]; float m = -1e30f;
    #pragma unroll
    for (int i = 0; i < 6; i++) {
        ushort4 u = *(const ushort4*)&x[i * 1024 + t * 4];
        float a0 = b2f(u.x), a1 = b2f(u.y), a2 = b2f(u.z), a3 = b2f(u.w);
        r[4*i] = a0; r[4*i+1] = a1; r[4*i+2] = a2; r[4*i+3] = a3;
        m = fmaxf(m, fmaxf(fmaxf(a0, a1), fmaxf(a2, a3)));
    }
    m = blk_max(m);
    float s = 0.f;
    #pragma unroll
    for (int i = 0; i < 24; i++) { r[i] = __expf(r[i] - m); s += r[i]; }
    s = blk_sum(s);
    float inv = 1.f / s;
    #pragma unroll
    for (int i = 0; i < 6; i++) {
        ushort4 u;
        u.x = f2b(r[4*i] * inv);   u.y = f2b(r[4*i+1] * inv);
        u.z = f2b(r[4*i+2] * inv); u.w = f2b(r[4*i+3] * inv);
        *(ushort4*)&x[i * 1024 + t * 4] = u;
    }
}

// ---------------- softmax bf16, W=512 ----------------
__global__ __launch_bounds__(256)
void softmax_b512(ushort* __restrict__ X)
{
    long long row = blockIdx.x;
    ushort* x = X + row * 512;
    int t = threadIdx.x;
    ushort2 u = *(const ushort2*)&x[t * 2];
    float a = b2f(u.x), b = b2f(u.y);
    float m = blk_max(fmaxf(a, b));
    a = __expf(a - m); b = __expf(b - m);
    float s = blk_sum(a + b);
    float inv = 1.f / s;
    u.x = f2b(a * inv); u.y = f2b(b * inv);
    *(ushort2*)&x[t * 2] = u;
}

// ---------------- LN + front-pad -> bf16 ----------------
__global__ __launch_bounds__(256)
void ln_pad(const float* __restrict__ H, const float* __restrict__ g,
            const float* __restrict__ b, ushort* __restrict__ X)
{
    int row = blockIdx.x, t = threadIdx.x;
    ushort* o = X + (long long)row * DIM;
    if (row < PAD) {
        #pragma unroll
        for (int i = 0; i < 4; i++) o[t + i * 256] = 0;
        return;
    }
    const float* x = H + (long long)(row - PAD) * DIM;
    float r[4]; float s = 0.f;
    #pragma unroll
    for (int i = 0; i < 4; i++) { r[i] = x[t + i * 256]; s += r[i]; }
    float mu = blk_sum(s) * (1.f / DIM);
    float v = 0.f;
    #pragma unroll
    for (int i = 0; i < 4; i++) { float d = r[i] - mu; v += d * d; }
    float var = blk_sum(v) * (1.f / DIM);
    float rs = rsqrtf(var + 1e-5f);
    #pragma unroll
    for (int i = 0; i < 4; i++) { int c = t + i * 256; o[c] = f2b((r[i] - mu) * rs * g[c] + b[c]); }
}

// ---------------- landmarks (bf16 in/out) ----------------
__global__ __launch_bounds__(128)
void landmarks(const ushort* __restrict__ QKVb, ushort* __restrict__ QL, ushort* __restrict__ KL)
{
    int L = blockIdx.x, h = blockIdx.y, d = threadIdx.x;
    float sq = 0.f, sk = 0.f;
    #pragma unroll
    for (int j = 0; j < LSUB; j++) {
        const ushort* p = QKVb + (long long)(L * LSUB + j) * 3072 + h * DHEAD + d;
        sq += b2f(p[0]);
        sk += b2f(p[1024]);
    }
    QL[(long long)(h * LMK + L) * DHEAD + d] = f2b(sq * (1.f / LSUB));
    KL[(long long)(h * LMK + L) * DHEAD + d] = f2b(sk * (1.f / LSUB));
}

// ---------------- V transpose -> bf16 VT[h][d][i] ----------------
__global__ void vtrans(const ushort* __restrict__ Q, ushort* __restrict__ VT)
{
    __shared__ ushort tile[32][33];
    int h = blockIdx.z, i0 = blockIdx.x * 32, d0 = blockIdx.y * 32;
    int tx = threadIdx.x, ty = threadIdx.y;
    for (int yy = ty; yy < 32; yy += 8)
        tile[yy][tx] = Q[(long long)(i0 + yy) * 3072 + 2048 + h * 128 + d0 + tx];
    __syncthreads();
    for (int yy = ty; yy < 32; yy += 8)
        VT[((long long)h * 128 + d0 + yy) * 6144 + i0 + tx] = tile[tx][yy];
}

// ---------------- a2 row/col sums + scalar ----------------
__global__ __launch_bounds__(256)
void a2_sums(const float* __restrict__ A2, float* __restrict__ cols, float* __restrict__ rows)
{
    int h = blockIdx.x, t = threadIdx.x;
    const float* a = A2 + (long long)h * LMK * LMK;
    for (int j = t; j < LMK; j += 256) {
        float s = 0.f;
        for (int i = 0; i < LMK; i++) s += fabsf(a[(long long)i * LMK + j]);
        cols[h * LMK + j] = s;
    }
    for (int r = t; r < LMK; r += 256) {
        float s = 0.f;
        const float* p = a + (long long)r * LMK;
        for (int j = 0; j < LMK; j++) s += fabsf(p[j]);
        rows[h * LMK + r] = s;
    }
}
__global__ __launch_bounds__(256)
void a2_scal(const float* __restrict__ cols, const float* __restrict__ rows, float* __restrict__ scal)
{
    float mc = -1e30f, mr = -1e30f;
    for (int i = threadIdx.x; i < HEADS * LMK; i += 256) {
        mc = fmaxf(mc, cols[i]); mr = fmaxf(mr, rows[i]);
    }
    mc = blk_max(mc); mr = blk_max(mr);
    if (threadIdx.x == 0) scal[0] = 1.f / (mc * mr);
}

// ---------------- z0 = a2^T * scal ----------------
__global__ void z0_t(const float* __restrict__ A2, float* __restrict__ Z, const float* __restrict__ scal)
{
    __shared__ float tile[32][33];
    int h = blockIdx.z;
    const float* a = A2 + (long long)h * LMK * LMK;
    float* z = Z + (long long)h * LMK * LMK;
    float s = scal[0];
    int x0 = blockIdx.x * 32, y0 = blockIdx.y * 32;
    int tx = threadIdx.x, ty = threadIdx.y;
    for (int yy = ty; yy < 32; yy += 8) tile[yy][tx] = a[(long long)(y0 + yy) * LMK + x0 + tx];
    __syncthreads();
    for (int yy = ty; yy < 32; yy += 8) z[(long long)(x0 + yy) * LMK + y0 + tx] = tile[tx][yy] * s;
}

// ---------------- MoE ----------------
__global__ __launch_bounds__(256)
void moe_combine(const float* __restrict__ X, const float* __restrict__ wg,
                 const float* __restrict__ EO, const float* __restrict__ eb,
                 float* __restrict__ H)
{
    int i = blockIdx.x, t = threadIdx.x;
    const float* x = X + (long long)i * INDIM;
    float g0 = 0.f, g1 = 0.f, g2 = 0.f;
    for (int f = t; f < INDIM; f += 256) {
        float xv = x[f];
        const float* w = wg + f * 3;
        g0 += xv * w[0]; g1 += xv * w[1]; g2 += xv * w[2];
    }
    g0 = blk_sum(g0); g1 = blk_sum(g1); g2 = blk_sum(g2);
    float m = fmaxf(g0, fmaxf(g1, g2));
    float e0 = __expf(g0 - m), e1 = __expf(g1 - m), e2 = __expf(g2 - m);
    float inv = 1.f / (e0 + e1 + e2);
    e0 *= inv; e1 *= inv; e2 *= inv;
    const float* eo = EO + (long long)i * 3072;
    for (int o = t; o < DIM; o += 256) {
        float v0 = fmaxf(eo[o]        + eb[o],        0.f);
        float v1 = fmaxf(eo[1024 + o] + eb[1024 + o], 0.f);
        float v2 = fmaxf(eo[2048 + o] + eb[2048 + o], 0.f);
        float r = e0 * v0 + e1 * v1 + e2 * v2;
        H[(long long)(1 + i) * DIM + o] = r;
        if (i < 84) H[(long long)(6001 + i) * DIM + o] = r;
    }
}

__global__ void cls_copy(const float* __restrict__ c, float* __restrict__ H)
{
    for (int i = threadIdx.x; i < DIM; i += 256) H[i] = c[i];
}

// ---------------- depthwise 33-tap res conv on V (bf16), added to O (f32) ----------------
__global__ __launch_bounds__(256)
void resconv(const ushort* __restrict__ QKVb, const float* __restrict__ rw, float* __restrict__ O)
{
    long long idx = (long long)blockIdx.x * 256 + threadIdx.x;
    int c = (int)(idx & 1023);
    long long i = idx >> 10;
    int h = c >> 7;
    float acc = 0.f;
    #pragma unroll
    for (int t = 0; t < 33; t++) {
        long long r = i + t - 16;
        if (r >= 0 && r < NPL) acc += rw[h * 33 + t] * b2f(QKVb[r * 3072 + 2048 + c]);
    }
    O[idx] += acc;
}

// ---------------- PPEG ----------------
__global__ void h2f(const float* __restrict__ H, float* __restrict__ F)
{
    __shared__ float tile[32][33];
    int p0 = blockIdx.x * 32, c0 = blockIdx.y * 32;
    int tx = threadIdx.x, ty = threadIdx.y;
    for (int yy = ty; yy < 32; yy += 8) {
        int p = p0 + yy;
        if (p < HW * HW) tile[yy][tx] = H[(long long)(1 + p) * DIM + c0 + tx];
    }
    __syncthreads();
    for (int yy = ty; yy < 32; yy += 8) {
        int p = p0 + tx, c = c0 + yy;
        if (p < HW * HW) F[(long long)c * (HW * HW) + p] = tile[tx][yy];
    }
}
__global__ void f2h(const float* __restrict__ F2, float* __restrict__ H)
{
    __shared__ float tile[32][33];
    int c0 = blockIdx.x * 32, p0 = blockIdx.y * 32;
    int tx = threadIdx.x, ty = threadIdx.y;
    for (int yy = ty; yy < 32; yy += 8) {
        int p = p0 + tx;
        if (p < HW * HW) tile[yy][tx] = F2[(long long)(c0 + yy) * (HW * HW) + p];
    }
    __syncthreads();
    for (int yy = ty; yy < 32; yy += 8) {
        int p = p0 + yy;
        if (p < HW * HW) H[(long long)(1 + p) * DIM + c0 + tx] = tile[tx][yy];
    }
}
__global__ __launch_bounds__(256)
void ppeg_conv(const float* __restrict__ F,
               const float* __restrict__ w7, const float* __restrict__ b7,
               const float* __restrict__ w5, const float* __restrict__ b5,
               const float* __restrict__ w3, const float* __restrict__ b3,
               float* __restrict__ F2)
{
    int c = blockIdx.x, t = threadIdx.x;
    __shared__ float plane[HW * HW];
    __shared__ float ws7[49], ws5[25], ws3[9];
    for (int p = t; p < HW * HW; p += 256) plane[p] = F[(long long)c * (HW * HW) + p];
    if (t < 49) ws7[t] = w7[(long long)c * 49 + t];
    if (t < 25) ws5[t] = w5[(long long)c * 25 + t];
    if (t < 9)  ws3[t] = w3[(long long)c * 9 + t];
    __syncthreads();
    float bsum = b7[c] + b5[c] + b3[c];
    for (int p = t; p < HW * HW; p += 256) {
        int y = p / HW, x = p - y * HW;
        float acc = plane[p] + bsum;
        for (int ky = -3; ky <= 3; ky++) {
            int yy = y + ky; if ((unsigned)yy >= (unsigned)HW) continue;
            for (int kx = -3; kx <= 3; kx++) {
                int xx = x + kx; if ((unsigned)xx >= (unsigned)HW) continue;
                acc += ws7[(ky + 3) * 7 + (kx + 3)] * plane[yy * HW + xx];
            }
        }
        for (int ky = -2; ky <= 2; ky++) {
            int yy = y + ky; if ((unsigned)yy >= (unsigned)HW) continue;
            for (int kx = -2; kx <= 2; kx++) {
                int xx = x + kx; if ((unsigned)xx >= (unsigned)HW) continue;
                acc += ws5[(ky + 2) * 5 + (kx + 2)] * plane[yy * HW + xx];
            }
        }
        for (int ky = -1; ky <= 1; ky++) {
            int yy = y + ky; if ((unsigned)yy >= (unsigned)HW) continue;
            for (int kx = -1; kx <= 1; kx++) {
                int xx = x + kx; if ((unsigned)xx >= (unsigned)HW) continue;
                acc += ws3[(ky + 1) * 3 + (kx + 1)] * plane[yy * HW + xx];
            }
        }
        F2[(long long)c * (HW * HW) + p] = acc;
    }
}

// ---------------- final head ----------------
__global__ __launch_bounds__(256)
void head_k(const float* __restrict__ H, const float* __restrict__ g, const float* __restrict__ b,
            const float* __restrict__ fw, const float* __restrict__ fb, float* __restrict__ out)
{
    int t = threadIdx.x;
    float r[4]; float s = 0.f;
    #pragma unroll
    for (int i = 0; i < 4; i++) { r[i] = H[t + i * 256]; s += r[i]; }
    float mu = blk_sum(s) * (1.f / DIM);
    float v = 0.f;
    #pragma unroll
    for (int i = 0; i < 4; i++) { float d = r[i] - mu; v += d * d; }
    float var = blk_sum(v) * (1.f / DIM);
    float rs = rsqrtf(var + 1e-5f);
    float d0 = 0.f, d1 = 0.f;
    #pragma unroll
    for (int i = 0; i < 4; i++) {
        int c = t + i * 256;
        float hv = (r[i] - mu) * rs * g[c] + b[c];
        d0 += hv * fw[c];
        d1 += hv * fw[DIM + c];
    }
    d0 = blk_sum(d0); d1 = blk_sum(d1);
    if (t == 0) {
        float l0 = d0 + fb[0], l1 = d1 + fb[1];
        float m = fmaxf(l0, l1);
        float e0 = __expf(l0 - m), e1 = __expf(l1 - m);
        float inv = 1.f / (e0 + e1);
        out[0] = l0; out[1] = l1;
        out[2] = e0 * inv; out[3] = e1 * inv;
        out[4] = (l1 > l0) ? 1.0f : 0.0f;
    }
}

// ---------------- host ----------------
extern "C" void kernel_launch(void* const* d_in, const int* in_sizes, int n_in,
                              void* d_out, int out_size, void* d_ws, size_t ws_size,
                              hipStream_t stream)
{
    const float* data     = (const float*)d_in[0];
    const float* w_gate   = (const float*)d_in[1];
    const float* expert_w = (const float*)d_in[2];
    const float* expert_b = (const float*)d_in[3];
    const float* cls_tok  = (const float*)d_in[4];
    const float* ln_g[2]  = {(const float*)d_in[5],  (const float*)d_in[11]};
    const float* ln_b[2]  = {(const float*)d_in[6],  (const float*)d_in[12]};
    const float* qkv_w[2] = {(const float*)d_in[7],  (const float*)d_in[13]};
    const float* out_w[2] = {(const float*)d_in[8],  (const float*)d_in[14]};
    const float* out_b[2] = {(const float*)d_in[9],  (const float*)d_in[15]};
    const float* res_w[2] = {(const float*)d_in[10], (const float*)d_in[16]};
    const float* pw7 = (const float*)d_in[17]; const float* pb7 = (const float*)d_in[18];
    const float* pw5 = (const float*)d_in[19]; const float* pb5 = (const float*)d_in[20];
    const float* pw3 = (const float*)d_in[21]; const float* pb3 = (const float*)d_in[22];
    const float* nf_g = (const float*)d_in[23]; const float* nf_b = (const float*)d_in[24];
    const float* fc2w = (const float*)d_in[25]; const float* fc2b = (const float*)d_in[26];

    float*  ws   = (float*)d_ws;
    float*  H    = ws + OFF_H;
    ushort* LNXb = (ushort*)(ws + OFF_LNXO);
    float*  O    = ws + OFF_LNXO;            // alias (O written after LNX dead)
    ushort* QKVb = (ushort*)(ws + OFF_QKVB);
    float*  EO   = ws + OFF_QKVB;            // alias (EO dead before QKVb written)
    ushort* S    = (ushort*)(ws + OFF_S);
    ushort* VT   = (ushort*)(ws + OFF_VT);
    ushort* QL   = (ushort*)(ws + OFF_QL);
    ushort* KL   = (ushort*)(ws + OFF_KL);
    float*  A2   = ws + OFF_A2;
    float*  Z    = ws + OFF_Z;
    float*  Z2   = ws + OFF_Z2;
    float*  XZ   = ws + OFF_XZ;
    float*  T1   = ws + OFF_T1;
    float*  T2   = ws + OFF_T2;
    float*  BV   = ws + OFF_BV;
    float*  ZBT  = ws + OFF_ZBT;
    float*  COLS = ws + OFF_COLS;
    float*  ROWS = ws + OFF_ROWS;
    float*  SCAL = ws + OFF_SCAL;

    const long long HSB = (long long)LMK * DHEAD;   // 65536 (bf16 or f32 elems)
    const long long A2S = (long long)LMK * LMK;     // 262144
    const long long SS  = (long long)LMK * NPL;     // 3145728

    // ---- MoE ----
    mgemm<0,0,float,float><<<dim3(24,47,1),256,0,stream>>>(data,INDIM,0, expert_w,INDIM,0,
        EO,3072,0, NTOK,INDIM, nullptr, 1.f,0.f,0.f);
    moe_combine<<<NTOK,256,0,stream>>>(data, w_gate, EO, expert_b, H);
    cls_copy<<<1,256,0,stream>>>(cls_tok, H);

    for (int stage = 0; stage < 2; stage++) {
        ln_pad<<<NPL,256,0,stream>>>(H, ln_g[stage], ln_b[stage], LNXb);
        // QKVb = LNX @ qkv_w^T (bf16 out, q scaled)
        mgemm<1,0,ushort,float><<<dim3(24,48,1),256,0,stream>>>(LNXb,DIM,0, qkv_w[stage],DIM,0,
            QKVb,3072,0, NPL,DIM, nullptr, 1.f,0.f,0.f);
        landmarks<<<dim3(LMK,HEADS),128,0,stream>>>(QKVb, QL, KL);
        vtrans<<<dim3(192,4,8),dim3(32,8),0,stream>>>(QKVb, VT);
        // a2 = softmax(ql @ kl^T)  (f32)
        mgemm<0,0,ushort,ushort><<<dim3(4,4,8),256,0,stream>>>(QL,DHEAD,HSB, KL,DHEAD,HSB,
            A2,LMK,A2S, LMK,DHEAD, nullptr, 1.f,0.f,0.f);
        softmax_rows<2><<<HEADS*LMK,256,0,stream>>>(A2, LMK);
        a2_sums<<<HEADS,256,0,stream>>>(A2, COLS, ROWS);
        a2_scal<<<1,256,0,stream>>>(COLS, ROWS, SCAL);
        z0_t<<<dim3(16,16,8),dim3(32,8),0,stream>>>(A2, Z, SCAL);
        // Newton-Schulz: iters 0-4 bf16 MFMA, iter 5 fp32
        float* zin = Z; float* zout = Z2;
        for (int it = 0; it < 6; it++) {
            if (it < 5) {
                mgemm<0,1,float,float><<<dim3(4,4,8),256,0,stream>>>(A2,LMK,A2S, zin,LMK,A2S,
                    XZ,LMK,A2S, LMK,LMK, nullptr, 1.f, 0.f, 1.f);
                mgemm<0,1,float,float><<<dim3(4,4,8),256,0,stream>>>(XZ,LMK,A2S, XZ,LMK,A2S,
                    T1,LMK,A2S, LMK,LMK, nullptr, 1.f, 7.f, -1.f);
                mgemm<0,1,float,float><<<dim3(4,4,8),256,0,stream>>>(XZ,LMK,A2S, T1,LMK,A2S,
                    T2,LMK,A2S, LMK,LMK, nullptr, 1.f, 15.f, -1.f);
                mgemm<0,1,float,float><<<dim3(4,4,8),256,0,stream>>>(zin,LMK,A2S, T2,LMK,A2S,
                    zout,LMK,A2S, LMK,LMK, nullptr, 0.25f, 13.f, -1.f);
            } else {
                gemm_nn<0><<<dim3(8,8,8),256,0,stream>>>(A2,LMK,A2S, zin,LMK,A2S,
                    XZ,LMK,A2S, LMK,LMK,LMK, 1.f, 0.f, 1.f);
                gemm_nn<0><<<dim3(8,8,8),256,0,stream>>>(XZ,LMK,A2S, XZ,LMK,A2S,
                    T1,LMK,A2S, LMK,LMK,LMK, 1.f, 7.f, -1.f);
                gemm_nn<0><<<dim3(8,8,8),256,0,stream>>>(XZ,LMK,A2S, T1,LMK,A2S,
                    T2,LMK,A2S, LMK,LMK,LMK, 1.f, 15.f, -1.f);
                gemm_nn<0><<<dim3(8,8,8),256,0,stream>>>(zin,LMK,A2S, T2,LMK,A2S,
                    zout,LMK,A2S, LMK,LMK,LMK, 0.25f, 13.f, -1.f);
            }
            float* tmp = zin; zin = zout; zout = tmp;
        }
        // a3 = softmax(ql @ k^T) -> S (bf16, batched)
        mgemm<2,0,ushort,ushort><<<dim3(48,4,8),256,0,stream>>>(QL,DHEAD,HSB, QKVb+1024,3072,128,
            S,NPL,SS, LMK,DHEAD, nullptr, 1.f,0.f,0.f);
        softmax_b6144<<<HEADS*LMK,256,0,stream>>>(S);
        // bv = a3 @ v   via VT
        mgemm<0,0,ushort,ushort><<<dim3(1,4,8),256,0,stream>>>(S,NPL,SS, VT,NPL,(long long)DHEAD*NPL,
            BV,DHEAD,HSB, LMK,NPL, nullptr, 1.f,0.f,0.f);
        // zbt = (z @ bv)^T  (fp32, transposed store)
        gemm_nn<1><<<dim3(2,8,8),256,0,stream>>>(zin,LMK,A2S, BV,DHEAD,HSB,
            ZBT,LMK,HSB, LMK,DHEAD,LMK, 1.f, 0.f, 1.f);
        // a1 = softmax(q @ kl^T) -> S (bf16, batched)
        mgemm<2,0,ushort,ushort><<<dim3(4,48,8),256,0,stream>>>(QKVb,3072,128, KL,DHEAD,HSB,
            S,LMK,SS, NPL,DHEAD, nullptr, 1.f,0.f,0.f);
        softmax_b512<<<HEADS*NPL,256,0,stream>>>(S);
        // O = a1 @ zb  (per-head cols via sC=128)
        mgemm<0,0,ushort,float><<<dim3(1,48,8),256,0,stream>>>(S,LMK,SS, ZBT,LMK,HSB,
            O,DIM,DHEAD, NPL,LMK, nullptr, 1.f,0.f,0.f);
        resconv<<<(NPL*DIM)/256,256,0,stream>>>(QKVb, res_w[stage], O);
        // H += O @ out_w^T + out_b
        mgemm<3,0,float,float><<<dim3(8,48,1),256,0,stream>>>(O+(long long)PAD*DIM,DIM,0,
            out_w[stage],DIM,0, H,DIM,0, NH,DIM, out_b[stage], 1.f,0.f,0.f);
        if (stage == 0) {
            float* F  = ws + OFF_QKVB;
            float* F2 = F + 6230016LL;
            h2f<<<dim3(191,32),dim3(32,8),0,stream>>>(H, F);
            ppeg_conv<<<DIM,256,0,stream>>>(F, pw7, pb7, pw5, pb5, pw3, pb3, F2);
            f2h<<<dim3(32,191),dim3(32,8),0,stream>>>(F2, H);
        }
    }

    head_k<<<1,256,0,stream>>>(H, nf_g, nf_b, fc2w, fc2b, (float*)d_out);
}

// Round 4
// 2380.378 us; speedup vs baseline: 4.8611x; 1.2992x over previous
//
#include <hip/hip_runtime.h>
#include <hip/hip_bf16.h>

// ---------------- constants ----------------
#define NTOK   6000
#define INDIM  1536
#define DIM    1024
#define NPL    6144
#define PAD    59
#define NH     6085
#define HEADS  8
#define DHEAD  128
#define LMK    512
#define LSUB   12
#define HW     78
#define QSCALE 0.08838834764831845f

// ---------------- ws layout (float-slot offsets), ~219 MB ----------------
#define OFF_H     0LL          // 6144*1024 f32
#define OFF_LNXO  6291456LL    // LNXb bf16 / O f32 alias
#define OFF_QKVB  12582912LL   // 6144*3072 bf16; EO f32 + PPEG planes spill into S
#define OFF_S     22020096LL   // 8*512*6144 bf16; aliases: XZF/T1F/T2F/ZF f32, Ob bf16
#define OFF_VT    34603008LL   // 8*128*6144 bf16
#define OFF_QL    37748736LL
#define OFF_KL    38010880LL
#define OFF_A2F   38273024LL   // 8*512*512 f32
#define OFF_Z5F   40370176LL   // 8*512*512 f32
#define OFF_XB    42467328LL   // bf16 8*512*512 each below
#define OFF_XZB   43515904LL
#define OFF_XZT7  44564480LL
#define OFF_PT15  45613056LL
#define OFF_QT13  46661632LL
#define OFF_ZB0   47710208LL
#define OFF_ZT0   48758784LL
#define OFF_ZB1   49807360LL
#define OFF_ZT1   50855936LL
#define OFF_BVF   51904512LL   // 8*512*128 f32
#define OFF_ZBT   52428800LL   // 8*128*512 bf16
#define OFF_QWB   52690944LL   // 3072*1024 bf16
#define OFF_OWB   54263808LL   // 1024*1024 bf16
#define OFF_COLS  54788096LL
#define OFF_ROWS  54792192LL
#define OFF_SCAL  54796288LL
// transient aliases (dead before overlapping buffers are written)
#define OFF_DATAB 31457280LL   // 6000*1536 bf16 (inside S/VT span, pre-stage only)
#define OFF_EWB   36065280LL   // 3072*1536 bf16 (inside VT/QL/KL/A2F span, pre-stage only)

typedef __attribute__((ext_vector_type(8))) short s16x8;
typedef __attribute__((ext_vector_type(4))) float f32x4;

// ---------------- bf16 helpers ----------------
__device__ __forceinline__ ushort f2b(float f) {
    union { float f; unsigned u; } v; v.f = f;
    return (ushort)((v.u + 0x7FFF + ((v.u >> 16) & 1)) >> 16);
}
__device__ __forceinline__ float b2f(ushort h) {
    union { unsigned u; float f; } v; v.u = ((unsigned)h) << 16; return v.f;
}

// async global->LDS, 16 bytes per lane; lds ptr must be wave-uniform
__device__ __forceinline__ void gld16(const void* g, void* l) {
    __builtin_amdgcn_global_load_lds((const __attribute__((address_space(1))) void*)g,
                                     (__attribute__((address_space(3))) void*)l, 16, 0, 0);
}

// ---------------- reductions (blockDim.x == 256) ----------------
__device__ __forceinline__ float blk_sum(float v) {
    __shared__ float sb[4];
    #pragma unroll
    for (int o = 32; o > 0; o >>= 1) v += __shfl_down(v, o);
    int lane = threadIdx.x & 63, w = threadIdx.x >> 6;
    __syncthreads();
    if (lane == 0) sb[w] = v;
    __syncthreads();
    return sb[0] + sb[1] + sb[2] + sb[3];
}
__device__ __forceinline__ float blk_max(float v) {
    __shared__ float sb[4];
    #pragma unroll
    for (int o = 32; o > 0; o >>= 1) v = fmaxf(v, __shfl_down(v, o));
    int lane = threadIdx.x & 63, w = threadIdx.x >> 6;
    __syncthreads();
    if (lane == 0) sb[w] = v;
    __syncthreads();
    return fmaxf(fmaxf(sb[0], sb[1]), fmaxf(sb[2], sb[3]));
}

// ================= MFMA GEMM (bf16 x bf16), C = alpha * A @ B^T =================
// A: M x K row-major bf16 (per-z stride sA); B: N x K row-major bf16 (N = 128*gridDim.x).
// Tile 128x128x32, 4 waves, global_load_lds staging, linear LDS [128][32].
// EPI: 0 f32 store | 1 bf16 store, cols<1024 * QSCALE | 2 bf16 store
//      3 f32 C += v + bias[c] | 4 bf16 C + bf16 T[c][r]=tdelta*(r==c)+tsign*v
//      5 bf16 T only          | 6 bf16 C + bf16 T + optional f32 F
//      8 f32 atomicAdd (split-K over ksplit chunks via blockIdx.z)
template<int EPI>
__global__ __launch_bounds__(256)
void mg(const ushort* __restrict__ A, int lda, long long sA,
        const ushort* __restrict__ B, int ldb, long long sB,
        void* __restrict__ Cp, int ldc, long long sC,
        void* __restrict__ Tp, int ldt, long long sT,
        float* __restrict__ Fp, long long sF,
        int M, int K, const float* __restrict__ bias,
        float alpha, float tdelta, float tsign, int ksplit)
{
    __shared__ ushort As[4096];
    __shared__ ushort Bs[4096];
    const int t = threadIdx.x;
    int z = blockIdx.z;
    int kstart = 0, kend = K;
    if (EPI == 8) { int ch = z % ksplit; z /= ksplit; int kc = K / ksplit; kstart = ch * kc; kend = kstart + kc; }
    const ushort* Ab = A + (long long)z * sA;
    const ushort* Bb = B + (long long)z * sB;
    const int row0 = blockIdx.y * 128, col0 = blockIdx.x * 128;
    const int w = t >> 6, lane = t & 63;
    const int l4 = lane >> 2, ls = (lane & 3) * 8;
    // chunk q covers rows q*16..q*16+15 of the tile; q = inst*4 + w
    const int q0 = w, q1 = 4 + w;
    int ar0 = row0 + q0 * 16 + l4; if (ar0 >= M) ar0 = M - 1;
    int ar1 = row0 + q1 * 16 + l4; if (ar1 >= M) ar1 = M - 1;
    const int br0 = col0 + q0 * 16 + l4;
    const int br1 = col0 + q1 * 16 + l4;
    const ushort* ap0 = Ab + (long long)ar0 * lda + ls;
    const ushort* ap1 = Ab + (long long)ar1 * lda + ls;
    const ushort* bp0 = Bb + (long long)br0 * ldb + ls;
    const ushort* bp1 = Bb + (long long)br1 * ldb + ls;
    ushort* asl0 = &As[q0 * 512];
    ushort* asl1 = &As[q1 * 512];
    ushort* bsl0 = &Bs[q0 * 512];
    ushort* bsl1 = &Bs[q1 * 512];

    const int wr = (w >> 1) * 64, wc = (w & 1) * 64;
    const int fr = lane & 15, fo = (lane >> 4) * 8;

    f32x4 acc[4][4];
    #pragma unroll
    for (int a = 0; a < 4; a++)
        #pragma unroll
        for (int b = 0; b < 4; b++)
            acc[a][b] = (f32x4){0.f, 0.f, 0.f, 0.f};

    for (int kt = kstart; kt < kend; kt += 32) {
        gld16(ap0 + kt, asl0);
        gld16(ap1 + kt, asl1);
        gld16(bp0 + kt, bsl0);
        gld16(bp1 + kt, bsl1);
        __syncthreads();
        s16x8 af[4], bf[4];
        #pragma unroll
        for (int a = 0; a < 4; a++) af[a] = *(const s16x8*)&As[(wr + a * 16 + fr) * 32 + fo];
        #pragma unroll
        for (int b = 0; b < 4; b++) bf[b] = *(const s16x8*)&Bs[(wc + b * 16 + fr) * 32 + fo];
        #pragma unroll
        for (int a = 0; a < 4; a++)
            #pragma unroll
            for (int b = 0; b < 4; b++)
                acc[a][b] = __builtin_amdgcn_mfma_f32_16x16x32_bf16(af[a], bf[b], acc[a][b], 0, 0, 0);
        __syncthreads();
    }

    const int er0 = row0 + wr + ((lane >> 4) << 2);
    const int ec0 = col0 + wc + fr;
    #pragma unroll
    for (int a = 0; a < 4; a++) {
        #pragma unroll
        for (int j = 0; j < 4; j++) {
            int r = er0 + a * 16 + j;
            if (r >= M) continue;
            #pragma unroll
            for (int b = 0; b < 4; b++) {
                int c = ec0 + b * 16;
                float v = alpha * acc[a][b][j];
                long long ci = z * sC + (long long)r * ldc + c;
                if constexpr (EPI == 0) ((float*)Cp)[ci] = v;
                else if constexpr (EPI == 1) ((ushort*)Cp)[ci] = f2b(c < 1024 ? v * QSCALE : v);
                else if constexpr (EPI == 2) ((ushort*)Cp)[ci] = f2b(v);
                else if constexpr (EPI == 3) ((float*)Cp)[ci] += v + bias[c];
                else if constexpr (EPI == 8) atomicAdd(&((float*)Cp)[ci], v);
                else {
                    ushort tv = f2b((r == c ? tdelta : 0.f) + tsign * v);
                    long long ti = z * sT + (long long)c * ldt + r;
                    if constexpr (EPI == 4) { ((ushort*)Cp)[ci] = f2b(v); ((ushort*)Tp)[ti] = tv; }
                    else if constexpr (EPI == 5) { ((ushort*)Tp)[ti] = tv; }
                    else { // 6
                        ((ushort*)Cp)[ci] = f2b(v);
                        ((ushort*)Tp)[ti] = tv;
                        if (Fp) Fp[z * sF + (long long)r * ldc + c] = v;
                    }
                }
            }
        }
    }
}

// ---------------- fp32 GEMM: C = alpha * A(M,K) @ (cdiag*I + sgn*B(K,N)) ----------------
// TS=0: f32 store; TS=1: bf16 transposed store C[c*ldc+r].
template<int TS>
__global__ __launch_bounds__(256)
void gemm_nn(const float* __restrict__ A, int lda, long long sA,
             const float* __restrict__ B, int ldb, long long sB,
             void* __restrict__ Cv, int ldc, long long sC,
             int M, int N, int K, float alpha, float cdiag, float sgn)
{
    A += blockIdx.z * sA; B += blockIdx.z * sB;
    __shared__ float As[16][68];
    __shared__ float Bs[16][68];
    const int t = threadIdx.x;
    const int tx = t & 15, ty = t >> 4;
    const int row0 = blockIdx.y * 64, col0 = blockIdx.x * 64;
    const int lr = t >> 2, lk = (t & 3) << 2;
    const int bk = t >> 4, bn = (t & 15) << 2;
    float acc[4][4] = {{0.f,0.f,0.f,0.f},{0.f,0.f,0.f,0.f},{0.f,0.f,0.f,0.f},{0.f,0.f,0.f,0.f}};
    for (int kt = 0; kt < K; kt += 16) {
        float4 av = *(const float4*)(A + (long long)(row0 + lr) * lda + kt + lk);
        As[lk+0][lr] = av.x; As[lk+1][lr] = av.y; As[lk+2][lr] = av.z; As[lk+3][lr] = av.w;
        float4 bvv = *(const float4*)(B + (long long)(kt + bk) * ldb + col0 + bn);
        int gk = kt + bk, gn = col0 + bn;
        Bs[bk][bn+0] = sgn * bvv.x + ((gk == gn+0) ? cdiag : 0.f);
        Bs[bk][bn+1] = sgn * bvv.y + ((gk == gn+1) ? cdiag : 0.f);
        Bs[bk][bn+2] = sgn * bvv.z + ((gk == gn+2) ? cdiag : 0.f);
        Bs[bk][bn+3] = sgn * bvv.w + ((gk == gn+3) ? cdiag : 0.f);
        __syncthreads();
        #pragma unroll
        for (int k = 0; k < 16; k++) {
            float aa[4], bb[4];
            *(float4*)aa = *(const float4*)&As[k][ty << 2];
            *(float4*)bb = *(const float4*)&Bs[k][tx << 2];
            #pragma unroll
            for (int i = 0; i < 4; i++)
                #pragma unroll
                for (int j = 0; j < 4; j++)
                    acc[i][j] = fmaf(aa[i], bb[j], acc[i][j]);
        }
        __syncthreads();
    }
    #pragma unroll
    for (int i = 0; i < 4; i++) {
        int r = row0 + (ty << 2) + i;
        #pragma unroll
        for (int j = 0; j < 4; j++) {
            int c = col0 + (tx << 2) + j;
            if (TS) ((ushort*)Cv)[blockIdx.z * sC + (long long)c * ldc + r] = f2b(alpha * acc[i][j]);
            else    ((float*)Cv)[blockIdx.z * sC + (long long)r * ldc + c] = alpha * acc[i][j];
        }
    }
}

// ---------------- f32 -> bf16 convert ----------------
__global__ __launch_bounds__(256)
void cvt_bf16(const float* __restrict__ x, ushort* __restrict__ y, long long n)
{
    long long i = ((long long)blockIdx.x * 256 + threadIdx.x) * 8;
    if (i >= n) return;
    float4 a = *(const float4*)(x + i), b = *(const float4*)(x + i + 4);
    ushort4 u0 = {f2b(a.x), f2b(a.y), f2b(a.z), f2b(a.w)};
    ushort4 u1 = {f2b(b.x), f2b(b.y), f2b(b.z), f2b(b.w)};
    *(ushort4*)(y + i) = u0; *(ushort4*)(y + i + 4) = u1;
}

// ---------------- softmax fp32 rows (W = NIT*256) ----------------
template<int NIT>
__global__ __launch_bounds__(256)
void softmax_rows(float* __restrict__ X, int W)
{
    long long row = blockIdx.x;
    float* x = X + row * W;
    float r[NIT];
    float m = -1e30f;
    #pragma unroll
    for (int i = 0; i < NIT; i++) { r[i] = x[threadIdx.x + i * 256]; m = fmaxf(m, r[i]); }
    m = blk_max(m);
    float s = 0.f;
    #pragma unroll
    for (int i = 0; i < NIT; i++) { r[i] = __expf(r[i] - m); s += r[i]; }
    s = blk_sum(s);
    float inv = 1.f / s;
    #pragma unroll
    for (int i = 0; i < NIT; i++) x[threadIdx.x + i * 256] = r[i] * inv;
}

// ---------------- softmax bf16, W=6144 ----------------
__global__ __launch_bounds__(256)
void softmax_b6144(ushort* __restrict__ X)
{
    long long row = blockIdx.x;
    ushort* x = X + row * 6144;
    int t = threadIdx.x;
    float r[24]; float m = -1e30f;
    #pragma unroll
    for (int i = 0; i < 6; i++) {
        ushort4 u = *(const ushort4*)&x[i * 1024 + t * 4];
        float a0 = b2f(u.x), a1 = b2f(u.y), a2 = b2f(u.z), a3 = b2f(u.w);
        r[4*i] = a0; r[4*i+1] = a1; r[4*i+2] = a2; r[4*i+3] = a3;
        m = fmaxf(m, fmaxf(fmaxf(a0, a1), fmaxf(a2, a3)));
    }
    m = blk_max(m);
    float s = 0.f;
    #pragma unroll
    for (int i = 0; i < 24; i++) { r[i] = __expf(r[i] - m); s += r[i]; }
    s = blk_sum(s);
    float inv = 1.f / s;
    #pragma unroll
    for (int i = 0; i < 6; i++) {
        ushort4 u;
        u.x = f2b(r[4*i] * inv);   u.y = f2b(r[4*i+1] * inv);
        u.z = f2b(r[4*i+2] * inv); u.w = f2b(r[4*i+3] * inv);
        *(ushort4*)&x[i * 1024 + t * 4] = u;
    }
}

// ---------------- softmax bf16, W=512 ----------------
__global__ __launch_bounds__(256)
void softmax_b512(ushort* __restrict__ X)
{
    long long row = blockIdx.x;
    ushort* x = X + row * 512;
    int t = threadIdx.x;
    ushort2 u = *(const ushort2*)&x[t * 2];
    float a = b2f(u.x), b = b2f(u.y);
    float m = blk_max(fmaxf(a, b));
    a = __expf(a - m); b = __expf(b - m);
    float s = blk_sum(a + b);
    float inv = 1.f / s;
    u.x = f2b(a * inv); u.y = f2b(b * inv);
    *(ushort2*)&x[t * 2] = u;
}

// ---------------- LN + front-pad -> bf16 ----------------
__global__ __launch_bounds__(256)
void ln_pad(const float* __restrict__ H, const float* __restrict__ g,
            const float* __restrict__ b, ushort* __restrict__ X)
{
    int row = blockIdx.x, t = threadIdx.x;
    ushort* o = X + (long long)row * DIM;
    if (row < PAD) {
        #pragma unroll
        for (int i = 0; i < 4; i++) o[t + i * 256] = 0;
        return;
    }
    const float* x = H + (long long)(row - PAD) * DIM;
    float r[4]; float s = 0.f;
    #pragma unroll
    for (int i = 0; i < 4; i++) { r[i] = x[t + i * 256]; s += r[i]; }
    float mu = blk_sum(s) * (1.f / DIM);
    float v = 0.f;
    #pragma unroll
    for (int i = 0; i < 4; i++) { float d = r[i] - mu; v += d * d; }
    float var = blk_sum(v) * (1.f / DIM);
    float rs = rsqrtf(var + 1e-5f);
    #pragma unroll
    for (int i = 0; i < 4; i++) { int c = t + i * 256; o[c] = f2b((r[i] - mu) * rs * g[c] + b[c]); }
}

// ---------------- landmarks ----------------
__global__ __launch_bounds__(128)
void landmarks(const ushort* __restrict__ QKVb, ushort* __restrict__ QL, ushort* __restrict__ KL)
{
    int L = blockIdx.x, h = blockIdx.y, d = threadIdx.x;
    float sq = 0.f, sk = 0.f;
    #pragma unroll
    for (int j = 0; j < LSUB; j++) {
        const ushort* p = QKVb + (long long)(L * LSUB + j) * 3072 + h * DHEAD + d;
        sq += b2f(p[0]);
        sk += b2f(p[1024]);
    }
    QL[(long long)(h * LMK + L) * DHEAD + d] = f2b(sq * (1.f / LSUB));
    KL[(long long)(h * LMK + L) * DHEAD + d] = f2b(sk * (1.f / LSUB));
}

// ---------------- V transpose -> bf16 VT[h][d][i] ----------------
__global__ void vtrans(const ushort* __restrict__ Q, ushort* __restrict__ VT)
{
    __shared__ ushort tile[32][33];
    int h = blockIdx.z, i0 = blockIdx.x * 32, d0 = blockIdx.y * 32;
    int tx = threadIdx.x, ty = threadIdx.y;
    for (int yy = ty; yy < 32; yy += 8)
        tile[yy][tx] = Q[(long long)(i0 + yy) * 3072 + 2048 + h * 128 + d0 + tx];
    __syncthreads();
    for (int yy = ty; yy < 32; yy += 8)
        VT[((long long)h * 128 + d0 + yy) * 6144 + i0 + tx] = tile[tx][yy];
}

// ---------------- a2 row/col sums + scalar ----------------
__global__ __launch_bounds__(256)
void a2_sums(const float* __restrict__ A2, float* __restrict__ cols, float* __restrict__ rows)
{
    int h = blockIdx.x, t = threadIdx.x;
    const float* a = A2 + (long long)h * LMK * LMK;
    for (int j = t; j < LMK; j += 256) {
        float s = 0.f;
        for (int i = 0; i < LMK; i++) s += fabsf(a[(long long)i * LMK + j]);
        cols[h * LMK + j] = s;
    }
    for (int r = t; r < LMK; r += 256) {
        float s = 0.f;
        const float* p = a + (long long)r * LMK;
        for (int j = 0; j < LMK; j++) s += fabsf(p[j]);
        rows[h * LMK + r] = s;
    }
}
__global__ __launch_bounds__(256)
void a2_scal(const float* __restrict__ cols, const float* __restrict__ rows, float* __restrict__ scal)
{
    float mc = -1e30f, mr = -1e30f;
    for (int i = threadIdx.x; i < HEADS * LMK; i += 256) {
        mc = fmaxf(mc, cols[i]); mr = fmaxf(mr, rows[i]);
    }
    mc = blk_max(mc); mr = blk_max(mr);
    if (threadIdx.x == 0) scal[0] = 1.f / (mc * mr);
}

// ---------------- z0/X prep: Xb = bf16(a2); Z0T = bf16(s*a2); Z0b = bf16(s*a2^T) ----------------
__global__ void z0_t(const float* __restrict__ A2, ushort* __restrict__ Xb,
                     ushort* __restrict__ Z0b, ushort* __restrict__ Z0T,
                     const float* __restrict__ scal)
{
    __shared__ float tile[32][33];
    int h = blockIdx.z;
    const float* a = A2 + (long long)h * LMK * LMK;
    float s = scal[0];
    int x0 = blockIdx.x * 32, y0 = blockIdx.y * 32;
    int tx = threadIdx.x, ty = threadIdx.y;
    long long hb = (long long)h * LMK * LMK;
    for (int yy = ty; yy < 32; yy += 8) {
        float v = a[(long long)(y0 + yy) * LMK + x0 + tx];
        tile[yy][tx] = v;
        Xb [hb + (long long)(y0 + yy) * LMK + x0 + tx] = f2b(v);
        Z0T[hb + (long long)(y0 + yy) * LMK + x0 + tx] = f2b(s * v);
    }
    __syncthreads();
    for (int yy = ty; yy < 32; yy += 8)
        Z0b[hb + (long long)(x0 + yy) * LMK + y0 + tx] = f2b(s * tile[tx][yy]);
}

// ---------------- MoE ----------------
__global__ __launch_bounds__(256)
void moe_combine(const float* __restrict__ X, const float* __restrict__ wg,
                 const float* __restrict__ EO, const float* __restrict__ eb,
                 float* __restrict__ H)
{
    int i = blockIdx.x, t = threadIdx.x;
    const float* x = X + (long long)i * INDIM;
    float g0 = 0.f, g1 = 0.f, g2 = 0.f;
    for (int f = t; f < INDIM; f += 256) {
        float xv = x[f];
        const float* w = wg + f * 3;
        g0 += xv * w[0]; g1 += xv * w[1]; g2 += xv * w[2];
    }
    g0 = blk_sum(g0); g1 = blk_sum(g1); g2 = blk_sum(g2);
    float m = fmaxf(g0, fmaxf(g1, g2));
    float e0 = __expf(g0 - m), e1 = __expf(g1 - m), e2 = __expf(g2 - m);
    float inv = 1.f / (e0 + e1 + e2);
    e0 *= inv; e1 *= inv; e2 *= inv;
    const float* eo = EO + (long long)i * 3072;
    for (int o = t; o < DIM; o += 256) {
        float v0 = fmaxf(eo[o]        + eb[o],        0.f);
        float v1 = fmaxf(eo[1024 + o] + eb[1024 + o], 0.f);
        float v2 = fmaxf(eo[2048 + o] + eb[2048 + o], 0.f);
        float r = e0 * v0 + e1 * v1 + e2 * v2;
        H[(long long)(1 + i) * DIM + o] = r;
        if (i < 84) H[(long long)(6001 + i) * DIM + o] = r;
    }
}

__global__ void cls_copy(const float* __restrict__ c, float* __restrict__ H)
{
    for (int i = threadIdx.x; i < DIM; i += 256) H[i] = c[i];
}

// ---------------- res conv: Ob = bf16(O + depthwise33(V)) ----------------
__global__ __launch_bounds__(256)
void resconv(const ushort* __restrict__ QKVb, const float* __restrict__ rw,
             const float* __restrict__ O, ushort* __restrict__ Ob)
{
    long long idx = (long long)blockIdx.x * 256 + threadIdx.x;
    int c = (int)(idx & 1023);
    long long i = idx >> 10;
    int h = c >> 7;
    float acc = O[idx];
    #pragma unroll
    for (int t = 0; t < 33; t++) {
        long long r = i + t - 16;
        if (r >= 0 && r < NPL) acc += rw[h * 33 + t] * b2f(QKVb[r * 3072 + 2048 + c]);
    }
    Ob[idx] = f2b(acc);
}

// ---------------- PPEG ----------------
__global__ void h2f(const float* __restrict__ H, float* __restrict__ F)
{
    __shared__ float tile[32][33];
    int p0 = blockIdx.x * 32, c0 = blockIdx.y * 32;
    int tx = threadIdx.x, ty = threadIdx.y;
    for (int yy = ty; yy < 32; yy += 8) {
        int p = p0 + yy;
        if (p < HW * HW) tile[yy][tx] = H[(long long)(1 + p) * DIM + c0 + tx];
    }
    __syncthreads();
    for (int yy = ty; yy < 32; yy += 8) {
        int p = p0 + tx, c = c0 + yy;
        if (p < HW * HW) F[(long long)c * (HW * HW) + p] = tile[tx][yy];
    }
}
__global__ void f2h(const float* __restrict__ F2, float* __restrict__ H)
{
    __shared__ float tile[32][33];
    int c0 = blockIdx.x * 32, p0 = blockIdx.y * 32;
    int tx = threadIdx.x, ty = threadIdx.y;
    for (int yy = ty; yy < 32; yy += 8) {
        int p = p0 + tx;
        if (p < HW * HW) tile[yy][tx] = F2[(long long)(c0 + yy) * (HW * HW) + p];
    }
    __syncthreads();
    for (int yy = ty; yy < 32; yy += 8) {
        int p = p0 + yy;
        if (p < HW * HW) H[(long long)(1 + p) * DIM + c0 + tx] = tile[tx][yy];
    }
}
__global__ __launch_bounds__(256)
void ppeg_conv(const float* __restrict__ F,
               const float* __restrict__ w7, const float* __restrict__ b7,
               const float* __restrict__ w5, const float* __restrict__ b5,
               const float* __restrict__ w3, const float* __restrict__ b3,
               float* __restrict__ F2)
{
    int c = blockIdx.x, t = threadIdx.x;
    __shared__ float plane[HW * HW];
    __shared__ float ws7[49], ws5[25], ws3[9];
    for (int p = t; p < HW * HW; p += 256) plane[p] = F[(long long)c * (HW * HW) + p];
    if (t < 49) ws7[t] = w7[(long long)c * 49 + t];
    if (t < 25) ws5[t] = w5[(long long)c * 25 + t];
    if (t < 9)  ws3[t] = w3[(long long)c * 9 + t];
    __syncthreads();
    float bsum = b7[c] + b5[c] + b3[c];
    for (int p = t; p < HW * HW; p += 256) {
        int y = p / HW, x = p - y * HW;
        float acc = plane[p] + bsum;
        for (int ky = -3; ky <= 3; ky++) {
            int yy = y + ky; if ((unsigned)yy >= (unsigned)HW) continue;
            for (int kx = -3; kx <= 3; kx++) {
                int xx = x + kx; if ((unsigned)xx >= (unsigned)HW) continue;
                acc += ws7[(ky + 3) * 7 + (kx + 3)] * plane[yy * HW + xx];
            }
        }
        for (int ky = -2; ky <= 2; ky++) {
            int yy = y + ky; if ((unsigned)yy >= (unsigned)HW) continue;
            for (int kx = -2; kx <= 2; kx++) {
                int xx = x + kx; if ((unsigned)xx >= (unsigned)HW) continue;
                acc += ws5[(ky + 2) * 5 + (kx + 2)] * plane[yy * HW + xx];
            }
        }
        for (int ky = -1; ky <= 1; ky++) {
            int yy = y + ky; if ((unsigned)yy >= (unsigned)HW) continue;
            for (int kx = -1; kx <= 1; kx++) {
                int xx = x + kx; if ((unsigned)xx >= (unsigned)HW) continue;
                acc += ws3[(ky + 1) * 3 + (kx + 1)] * plane[yy * HW + xx];
            }
        }
        F2[(long long)c * (HW * HW) + p] = acc;
    }
}

// ---------------- final head ----------------
__global__ __launch_bounds__(256)
void head_k(const float* __restrict__ H, const float* __restrict__ g, const float* __restrict__ b,
            const float* __restrict__ fw, const float* __restrict__ fb, float* __restrict__ out)
{
    int t = threadIdx.x;
    float r[4]; float s = 0.f;
    #pragma unroll
    for (int i = 0; i < 4; i++) { r[i] = H[t + i * 256]; s += r[i]; }
    float mu = blk_sum(s) * (1.f / DIM);
    float v = 0.f;
    #pragma unroll
    for (int i = 0; i < 4; i++) { float d = r[i] - mu; v += d * d; }
    float var = blk_sum(v) * (1.f / DIM);
    float rs = rsqrtf(var + 1e-5f);
    float d0 = 0.f, d1 = 0.f;
    #pragma unroll
    for (int i = 0; i < 4; i++) {
        int c = t + i * 256;
        float hv = (r[i] - mu) * rs * g[c] + b[c];
        d0 += hv * fw[c];
        d1 += hv * fw[DIM + c];
    }
    d0 = blk_sum(d0); d1 = blk_sum(d1);
    if (t == 0) {
        float l0 = d0 + fb[0], l1 = d1 + fb[1];
        float m = fmaxf(l0, l1);
        float e0 = __expf(l0 - m), e1 = __expf(l1 - m);
        float inv = 1.f / (e0 + e1);
        out[0] = l0; out[1] = l1;
        out[2] = e0 * inv; out[3] = e1 * inv;
        out[4] = (l1 > l0) ? 1.0f : 0.0f;
    }
}

// ---------------- host ----------------
extern "C" void kernel_launch(void* const* d_in, const int* in_sizes, int n_in,
                              void* d_out, int out_size, void* d_ws, size_t ws_size,
                              hipStream_t stream)
{
    const float* data     = (const float*)d_in[0];
    const float* w_gate   = (const float*)d_in[1];
    const float* expert_w = (const float*)d_in[2];
    const float* expert_b = (const float*)d_in[3];
    const float* cls_tok  = (const float*)d_in[4];
    const float* ln_g[2]  = {(const float*)d_in[5],  (const float*)d_in[11]};
    const float* ln_b[2]  = {(const float*)d_in[6],  (const float*)d_in[12]};
    const float* qkv_w[2] = {(const float*)d_in[7],  (const float*)d_in[13]};
    const float* out_w[2] = {(const float*)d_in[8],  (const float*)d_in[14]};
    const float* out_b[2] = {(const float*)d_in[9],  (const float*)d_in[15]};
    const float* res_w[2] = {(const float*)d_in[10], (const float*)d_in[16]};
    const float* pw7 = (const float*)d_in[17]; const float* pb7 = (const float*)d_in[18];
    const float* pw5 = (const float*)d_in[19]; const float* pb5 = (const float*)d_in[20];
    const float* pw3 = (const float*)d_in[21]; const float* pb3 = (const float*)d_in[22];
    const float* nf_g = (const float*)d_in[23]; const float* nf_b = (const float*)d_in[24];
    const float* fc2w = (const float*)d_in[25]; const float* fc2b = (const float*)d_in[26];

    float*  ws    = (float*)d_ws;
    float*  H     = ws + OFF_H;
    ushort* LNXb  = (ushort*)(ws + OFF_LNXO);
    float*  O     = ws + OFF_LNXO;
    ushort* QKVb  = (ushort*)(ws + OFF_QKVB);
    float*  EO    = ws + OFF_QKVB;            // spills into S pre-stage (ok)
    ushort* S     = (ushort*)(ws + OFF_S);
    float*  XZF   = ws + OFF_S;               // final-iter f32 scratch aliases S
    float*  T1F   = ws + OFF_S + 2097152;
    float*  T2F   = ws + OFF_S + 4194304;
    float*  ZF    = ws + OFF_S + 6291456;     // z4 f32
    ushort* Ob    = (ushort*)(ws + OFF_S);    // bf16 attn-out (after S dead)
    ushort* VT    = (ushort*)(ws + OFF_VT);
    ushort* QL    = (ushort*)(ws + OFF_QL);
    ushort* KL    = (ushort*)(ws + OFF_KL);
    float*  A2F   = ws + OFF_A2F;
    float*  Z5F   = ws + OFF_Z5F;
    ushort* Xb    = (ushort*)(ws + OFF_XB);
    ushort* XZB   = (ushort*)(ws + OFF_XZB);
    ushort* XZT7  = (ushort*)(ws + OFF_XZT7);
    ushort* PT15  = (ushort*)(ws + OFF_PT15);
    ushort* QT13  = (ushort*)(ws + OFF_QT13);
    ushort* ZB[2] = {(ushort*)(ws + OFF_ZB0), (ushort*)(ws + OFF_ZB1)};
    ushort* ZT[2] = {(ushort*)(ws + OFF_ZT0), (ushort*)(ws + OFF_ZT1)};
    float*  BVF   = ws + OFF_BVF;
    ushort* ZBT   = (ushort*)(ws + OFF_ZBT);
    ushort* QWB   = (ushort*)(ws + OFF_QWB);
    ushort* OWB   = (ushort*)(ws + OFF_OWB);
    ushort* DATAB = (ushort*)(ws + OFF_DATAB);
    ushort* EWB   = (ushort*)(ws + OFF_EWB);
    float*  COLS  = ws + OFF_COLS;
    float*  ROWS  = ws + OFF_ROWS;
    float*  SCAL  = ws + OFF_SCAL;

    const long long HSB = (long long)LMK * DHEAD;   // 65536
    const long long A2S = (long long)LMK * LMK;     // 262144
    const long long SS  = (long long)LMK * NPL;     // 3145728

    // ---- MoE ----
    cvt_bf16<<<4500, 256, 0, stream>>>(data, DATAB, (long long)NTOK * INDIM);
    cvt_bf16<<<2304, 256, 0, stream>>>(expert_w, EWB, 3072LL * INDIM);
    mg<0><<<dim3(24,47,1),256,0,stream>>>(DATAB,INDIM,0, EWB,INDIM,0, EO,3072,0,
        nullptr,0,0, nullptr,0, NTOK,INDIM, nullptr, 1.f,0.f,0.f,1);
    moe_combine<<<NTOK,256,0,stream>>>(data, w_gate, EO, expert_b, H);
    cls_copy<<<1,256,0,stream>>>(cls_tok, H);

    for (int stage = 0; stage < 2; stage++) {
        cvt_bf16<<<1536, 256, 0, stream>>>(qkv_w[stage], QWB, 3072LL * DIM);
        cvt_bf16<<<512, 256, 0, stream>>>(out_w[stage], OWB, (long long)DIM * DIM);
        ln_pad<<<NPL,256,0,stream>>>(H, ln_g[stage], ln_b[stage], LNXb);
        // QKVb = LNX @ qkv_w^T (bf16 out, q scaled)
        mg<1><<<dim3(24,48,1),256,0,stream>>>(LNXb,DIM,0, QWB,DIM,0, QKVb,3072,0,
            nullptr,0,0, nullptr,0, NPL,DIM, nullptr, 1.f,0.f,0.f,1);
        landmarks<<<dim3(LMK,HEADS),128,0,stream>>>(QKVb, QL, KL);
        vtrans<<<dim3(192,4,8),dim3(32,8),0,stream>>>(QKVb, VT);
        // a2 = softmax(ql @ kl^T) f32
        mg<0><<<dim3(4,4,8),256,0,stream>>>(QL,DHEAD,HSB, KL,DHEAD,HSB, A2F,LMK,A2S,
            nullptr,0,0, nullptr,0, LMK,DHEAD, nullptr, 1.f,0.f,0.f,1);
        softmax_rows<2><<<HEADS*LMK,256,0,stream>>>(A2F, LMK);
        a2_sums<<<HEADS,256,0,stream>>>(A2F, COLS, ROWS);
        a2_scal<<<1,256,0,stream>>>(COLS, ROWS, SCAL);
        z0_t<<<dim3(16,16,8),dim3(32,8),0,stream>>>(A2F, Xb, ZB[0], ZT[0], SCAL);
        // Newton-Schulz iters 0..4 (bf16 MFMA, transpose-affine epilogues)
        int cur = 0;
        for (int it = 0; it < 5; it++) {
            // G1: XZ = X @ z ; out: XZB (bf16), XZT7 = 7I - XZ^T
            mg<4><<<dim3(4,4,8),256,0,stream>>>(Xb,LMK,A2S, ZT[cur],LMK,A2S, XZB,LMK,A2S,
                XZT7,LMK,A2S, nullptr,0, LMK,LMK, nullptr, 1.f, 7.f, -1.f, 1);
            // G2: P = XZ @ (7I - XZ) ; out: PT15 = 15I - P^T
            mg<5><<<dim3(4,4,8),256,0,stream>>>(XZB,LMK,A2S, XZT7,LMK,A2S, nullptr,0,0,
                PT15,LMK,A2S, nullptr,0, LMK,LMK, nullptr, 1.f, 15.f, -1.f, 1);
            // G3: Q = XZ @ (15I - P) ; out: QT13 = 13I - Q^T
            mg<5><<<dim3(4,4,8),256,0,stream>>>(XZB,LMK,A2S, PT15,LMK,A2S, nullptr,0,0,
                QT13,LMK,A2S, nullptr,0, LMK,LMK, nullptr, 1.f, 13.f, -1.f, 1);
            // G4: z' = 0.25 z @ (13I - Q) ; out: ZB/ZT (+ f32 on last iter)
            mg<6><<<dim3(4,4,8),256,0,stream>>>(ZB[cur],LMK,A2S, QT13,LMK,A2S, ZB[1-cur],LMK,A2S,
                ZT[1-cur],LMK,A2S, (it == 4 ? ZF : nullptr),A2S, LMK,LMK, nullptr, 0.25f, 0.f, 1.f, 1);
            cur = 1 - cur;
        }
        // final Newton iteration in fp32 (scrubs bf16 noise)
        gemm_nn<0><<<dim3(8,8,8),256,0,stream>>>(A2F,LMK,A2S, ZF,LMK,A2S, XZF,LMK,A2S,
            LMK,LMK,LMK, 1.f, 0.f, 1.f);
        gemm_nn<0><<<dim3(8,8,8),256,0,stream>>>(XZF,LMK,A2S, XZF,LMK,A2S, T1F,LMK,A2S,
            LMK,LMK,LMK, 1.f, 7.f, -1.f);
        gemm_nn<0><<<dim3(8,8,8),256,0,stream>>>(XZF,LMK,A2S, T1F,LMK,A2S, T2F,LMK,A2S,
            LMK,LMK,LMK, 1.f, 15.f, -1.f);
        gemm_nn<0><<<dim3(8,8,8),256,0,stream>>>(ZF,LMK,A2S, T2F,LMK,A2S, Z5F,LMK,A2S,
            LMK,LMK,LMK, 0.25f, 13.f, -1.f);
        // a3 = softmax(ql @ k^T) -> S bf16
        mg<2><<<dim3(48,4,8),256,0,stream>>>(QL,DHEAD,HSB, QKVb+1024,3072,128, S,NPL,SS,
            nullptr,0,0, nullptr,0, LMK,DHEAD, nullptr, 1.f,0.f,0.f,1);
        softmax_b6144<<<HEADS*LMK,256,0,stream>>>(S);
        // bv = a3 @ v (split-K 8, atomic f32)
        hipMemsetAsync(BVF, 0, (size_t)HEADS * LMK * DHEAD * 4, stream);
        mg<8><<<dim3(1,4,64),256,0,stream>>>(S,NPL,SS, VT,NPL,(long long)DHEAD*NPL, BVF,DHEAD,HSB,
            nullptr,0,0, nullptr,0, LMK,NPL, nullptr, 1.f,0.f,0.f, 8);
        // zbt = (z5 @ bv)^T -> bf16
        gemm_nn<1><<<dim3(2,8,8),256,0,stream>>>(Z5F,LMK,A2S, BVF,DHEAD,HSB, ZBT,LMK,HSB,
            LMK,DHEAD,LMK, 1.f, 0.f, 1.f);
        // a1 = softmax(q @ kl^T) -> S bf16
        mg<2><<<dim3(4,48,8),256,0,stream>>>(QKVb,3072,128, KL,DHEAD,HSB, S,LMK,SS,
            nullptr,0,0, nullptr,0, NPL,DHEAD, nullptr, 1.f,0.f,0.f,1);
        softmax_b512<<<HEADS*NPL,256,0,stream>>>(S);
        // O = a1 @ zb (f32, per-head 128-col slabs)
        mg<0><<<dim3(1,48,8),256,0,stream>>>(S,LMK,SS, ZBT,LMK,HSB, O,DIM,128,
            nullptr,0,0, nullptr,0, NPL,LMK, nullptr, 1.f,0.f,0.f,1);
        // Ob = bf16(O + res conv of v)
        resconv<<<(NPL*DIM)/256,256,0,stream>>>(QKVb, res_w[stage], O, Ob);
        // H += Ob @ out_w^T + out_b
        mg<3><<<dim3(8,48,1),256,0,stream>>>(Ob + (long long)PAD*DIM,DIM,0, OWB,DIM,0, H,DIM,0,
            nullptr,0,0, nullptr,0, NH,DIM, out_b[stage], 1.f,0.f,0.f,1);
        if (stage == 0) {
            float* F  = ws + OFF_QKVB;
            float* F2 = F + 6230016LL;
            h2f<<<dim3(191,32),dim3(32,8),0,stream>>>(H, F);
            ppeg_conv<<<DIM,256,0,stream>>>(F, pw7, pb7, pw5, pb5, pw3, pb3, F2);
            f2h<<<dim3(32,191),dim3(32,8),0,stream>>>(F2, H);
        }
    }

    head_k<<<1,256,0,stream>>>(H, nf_g, nf_b, fc2w, fc2b, (float*)d_out);
}

// Round 5
// 2130.885 us; speedup vs baseline: 5.4302x; 1.1171x over previous
//
#include <hip/hip_runtime.h>
#include <hip/hip_bf16.h>

// ---------------- constants ----------------
#define NTOK   6000
#define INDIM  1536
#define DIM    1024
#define NPL    6144
#define PAD    59
#define NH     6085
#define HEADS  8
#define DHEAD  128
#define LMK    512
#define LSUB   12
#define HW     78
#define QSCALE 0.08838834764831845f

// ---------------- ws layout (float-slot offsets) ----------------
#define OFF_H     0LL          // 6144*1024 f32
#define OFF_LNXO  6291456LL    // LNXb bf16 / O f32 alias
#define OFF_QKVB  12582912LL   // 6144*3072 bf16; EO f32 + PPEG planes spill into S
#define OFF_S     22020096LL   // 8*512*6144 bf16; Ob bf16 alias
#define OFF_VT    34603008LL   // 8*128*6144 bf16
#define OFF_QL    37748736LL
#define OFF_KL    38010880LL
#define OFF_A2F   38273024LL   // 8*512*512 f32
#define OFF_BVTB  40370176LL   // 8*128*512 bf16 (262144 slots)
#define OFF_XB    42467328LL   // bf16 8*512*512 each below
#define OFF_XZB   43515904LL
#define OFF_XZT7  44564480LL
#define OFF_PT15  45613056LL
#define OFF_QT13  46661632LL
#define OFF_ZB0   47710208LL
#define OFF_ZT0   48758784LL
#define OFF_ZB1   49807360LL
#define OFF_ZT1   50855936LL
#define OFF_BVT   51904512LL   // 8*128*512 f32 (atomic, transposed)
#define OFF_ZBT   52428800LL   // 8*128*512 bf16
#define OFF_QWB   52690944LL   // 3072*1024 bf16
#define OFF_OWB   54263808LL   // 1024*1024 bf16
#define OFF_COLS  54788096LL
#define OFF_SCAL  54796288LL
// transient aliases (dead before overlapping buffers are written)
#define OFF_DATAB 31457280LL   // 6000*1536 bf16 (inside S/VT span, pre-stage only)
#define OFF_EWB   36065280LL   // 3072*1536 bf16 (inside VT/QL/KL/A2F span, pre-stage only)

typedef __attribute__((ext_vector_type(8))) short s16x8;
typedef __attribute__((ext_vector_type(4))) float f32x4;

// ---------------- bf16 helpers ----------------
__device__ __forceinline__ ushort f2b(float f) {
    union { float f; unsigned u; } v; v.f = f;
    return (ushort)((v.u + 0x7FFF + ((v.u >> 16) & 1)) >> 16);
}
__device__ __forceinline__ float b2f(ushort h) {
    union { unsigned u; float f; } v; v.u = ((unsigned)h) << 16; return v.f;
}

// async global->LDS, 16 bytes per lane; lds ptr must be wave-uniform
__device__ __forceinline__ void gld16(const void* g, void* l) {
    __builtin_amdgcn_global_load_lds((const __attribute__((address_space(1))) void*)g,
                                     (__attribute__((address_space(3))) void*)l, 16, 0, 0);
}

// ---------------- reductions (blockDim.x == 256) ----------------
__device__ __forceinline__ float blk_sum(float v) {
    __shared__ float sb[4];
    #pragma unroll
    for (int o = 32; o > 0; o >>= 1) v += __shfl_down(v, o);
    int lane = threadIdx.x & 63, w = threadIdx.x >> 6;
    __syncthreads();
    if (lane == 0) sb[w] = v;
    __syncthreads();
    return sb[0] + sb[1] + sb[2] + sb[3];
}
__device__ __forceinline__ float blk_max(float v) {
    __shared__ float sb[4];
    #pragma unroll
    for (int o = 32; o > 0; o >>= 1) v = fmaxf(v, __shfl_down(v, o));
    int lane = threadIdx.x & 63, w = threadIdx.x >> 6;
    __syncthreads();
    if (lane == 0) sb[w] = v;
    __syncthreads();
    return fmaxf(fmaxf(sb[0], sb[1]), fmaxf(sb[2], sb[3]));
}

// ================= MFMA GEMM (bf16 x bf16), C = alpha * A @ B^T =================
// A: M x K row-major bf16 (per-z stride sA); B: N x K row-major bf16 (N = 128*gridDim.x).
// Tile 128x128x32, 4 waves, global_load_lds staging, linear LDS [128][32].
// EPI: 0 f32 store | 1 bf16 store, cols<1024 * QSCALE | 2 bf16 store
//      3 f32 C += v + bias[c] | 4 bf16 C + bf16 T[c][r]=tdelta*(r==c)+tsign*v
//      5 bf16 T only          | 8 f32 atomicAdd (split-K via blockIdx.z)
//      9 f32 atomicAdd transposed C[c*ldc+r] (split-K via blockIdx.z)
template<int EPI>
__global__ __launch_bounds__(256)
void mg(const ushort* __restrict__ A, int lda, long long sA,
        const ushort* __restrict__ B, int ldb, long long sB,
        void* __restrict__ Cp, int ldc, long long sC,
        void* __restrict__ Tp, int ldt, long long sT,
        int M, int K, const float* __restrict__ bias,
        float alpha, float tdelta, float tsign, int ksplit)
{
    __shared__ ushort As[4096];
    __shared__ ushort Bs[4096];
    const int t = threadIdx.x;
    int z = blockIdx.z;
    int kstart = 0, kend = K;
    if (EPI == 8 || EPI == 9) { int ch = z % ksplit; z /= ksplit; int kc = K / ksplit; kstart = ch * kc; kend = kstart + kc; }
    const ushort* Ab = A + (long long)z * sA;
    const ushort* Bb = B + (long long)z * sB;
    const int row0 = blockIdx.y * 128, col0 = blockIdx.x * 128;
    const int w = t >> 6, lane = t & 63;
    const int l4 = lane >> 2, ls = (lane & 3) * 8;
    const int q0 = w, q1 = 4 + w;
    int ar0 = row0 + q0 * 16 + l4; if (ar0 >= M) ar0 = M - 1;
    int ar1 = row0 + q1 * 16 + l4; if (ar1 >= M) ar1 = M - 1;
    const int br0 = col0 + q0 * 16 + l4;
    const int br1 = col0 + q1 * 16 + l4;
    const ushort* ap0 = Ab + (long long)ar0 * lda + ls;
    const ushort* ap1 = Ab + (long long)ar1 * lda + ls;
    const ushort* bp0 = Bb + (long long)br0 * ldb + ls;
    const ushort* bp1 = Bb + (long long)br1 * ldb + ls;
    ushort* asl0 = &As[q0 * 512];
    ushort* asl1 = &As[q1 * 512];
    ushort* bsl0 = &Bs[q0 * 512];
    ushort* bsl1 = &Bs[q1 * 512];

    const int wr = (w >> 1) * 64, wc = (w & 1) * 64;
    const int fr = lane & 15, fo = (lane >> 4) * 8;

    f32x4 acc[4][4];
    #pragma unroll
    for (int a = 0; a < 4; a++)
        #pragma unroll
        for (int b = 0; b < 4; b++)
            acc[a][b] = (f32x4){0.f, 0.f, 0.f, 0.f};

    for (int kt = kstart; kt < kend; kt += 32) {
        gld16(ap0 + kt, asl0);
        gld16(ap1 + kt, asl1);
        gld16(bp0 + kt, bsl0);
        gld16(bp1 + kt, bsl1);
        __syncthreads();
        s16x8 af[4], bf[4];
        #pragma unroll
        for (int a = 0; a < 4; a++) af[a] = *(const s16x8*)&As[(wr + a * 16 + fr) * 32 + fo];
        #pragma unroll
        for (int b = 0; b < 4; b++) bf[b] = *(const s16x8*)&Bs[(wc + b * 16 + fr) * 32 + fo];
        #pragma unroll
        for (int a = 0; a < 4; a++)
            #pragma unroll
            for (int b = 0; b < 4; b++)
                acc[a][b] = __builtin_amdgcn_mfma_f32_16x16x32_bf16(af[a], bf[b], acc[a][b], 0, 0, 0);
        __syncthreads();
    }

    const int er0 = row0 + wr + ((lane >> 4) << 2);
    const int ec0 = col0 + wc + fr;
    #pragma unroll
    for (int a = 0; a < 4; a++) {
        #pragma unroll
        for (int j = 0; j < 4; j++) {
            int r = er0 + a * 16 + j;
            if (r >= M) continue;
            #pragma unroll
            for (int b = 0; b < 4; b++) {
                int c = ec0 + b * 16;
                float v = alpha * acc[a][b][j];
                long long ci = z * sC + (long long)r * ldc + c;
                if constexpr (EPI == 0) ((float*)Cp)[ci] = v;
                else if constexpr (EPI == 1) ((ushort*)Cp)[ci] = f2b(c < 1024 ? v * QSCALE : v);
                else if constexpr (EPI == 2) ((ushort*)Cp)[ci] = f2b(v);
                else if constexpr (EPI == 3) ((float*)Cp)[ci] += v + bias[c];
                else if constexpr (EPI == 8) atomicAdd(&((float*)Cp)[ci], v);
                else if constexpr (EPI == 9) atomicAdd(&((float*)Cp)[z * sC + (long long)c * ldc + r], v);
                else {
                    ushort tv = f2b((r == c ? tdelta : 0.f) + tsign * v);
                    long long ti = z * sT + (long long)c * ldt + r;
                    if constexpr (EPI == 4) { ((ushort*)Cp)[ci] = f2b(v); ((ushort*)Tp)[ti] = tv; }
                    else { ((ushort*)Tp)[ti] = tv; }  // 5
                }
            }
        }
    }
}

// ---------------- f32 -> bf16 convert ----------------
__global__ __launch_bounds__(256)
void cvt_bf16(const float* __restrict__ x, ushort* __restrict__ y, long long n)
{
    long long i = ((long long)blockIdx.x * 256 + threadIdx.x) * 8;
    if (i >= n) return;
    float4 a = *(const float4*)(x + i), b = *(const float4*)(x + i + 4);
    ushort4 u0 = {f2b(a.x), f2b(a.y), f2b(a.z), f2b(a.w)};
    ushort4 u1 = {f2b(b.x), f2b(b.y), f2b(b.z), f2b(b.w)};
    *(ushort4*)(y + i) = u0; *(ushort4*)(y + i + 4) = u1;
}

// ---------------- softmax fp32 rows (W = NIT*256) ----------------
template<int NIT>
__global__ __launch_bounds__(256)
void softmax_rows(float* __restrict__ X, int W)
{
    long long row = blockIdx.x;
    float* x = X + row * W;
    float r[NIT];
    float m = -1e30f;
    #pragma unroll
    for (int i = 0; i < NIT; i++) { r[i] = x[threadIdx.x + i * 256]; m = fmaxf(m, r[i]); }
    m = blk_max(m);
    float s = 0.f;
    #pragma unroll
    for (int i = 0; i < NIT; i++) { r[i] = __expf(r[i] - m); s += r[i]; }
    s = blk_sum(s);
    float inv = 1.f / s;
    #pragma unroll
    for (int i = 0; i < NIT; i++) x[threadIdx.x + i * 256] = r[i] * inv;
}

// ---------------- softmax bf16, W=6144 ----------------
__global__ __launch_bounds__(256)
void softmax_b6144(ushort* __restrict__ X)
{
    long long row = blockIdx.x;
    ushort* x = X + row * 6144;
    int t = threadIdx.x;
    float r[24]; float m = -1e30f;
    #pragma unroll
    for (int i = 0; i < 6; i++) {
        ushort4 u = *(const ushort4*)&x[i * 1024 + t * 4];
        float a0 = b2f(u.x), a1 = b2f(u.y), a2 = b2f(u.z), a3 = b2f(u.w);
        r[4*i] = a0; r[4*i+1] = a1; r[4*i+2] = a2; r[4*i+3] = a3;
        m = fmaxf(m, fmaxf(fmaxf(a0, a1), fmaxf(a2, a3)));
    }
    m = blk_max(m);
    float s = 0.f;
    #pragma unroll
    for (int i = 0; i < 24; i++) { r[i] = __expf(r[i] - m); s += r[i]; }
    s = blk_sum(s);
    float inv = 1.f / s;
    #pragma unroll
    for (int i = 0; i < 6; i++) {
        ushort4 u;
        u.x = f2b(r[4*i] * inv);   u.y = f2b(r[4*i+1] * inv);
        u.z = f2b(r[4*i+2] * inv); u.w = f2b(r[4*i+3] * inv);
        *(ushort4*)&x[i * 1024 + t * 4] = u;
    }
}

// ---------------- softmax bf16, W=512 ----------------
__global__ __launch_bounds__(256)
void softmax_b512(ushort* __restrict__ X)
{
    long long row = blockIdx.x;
    ushort* x = X + row * 512;
    int t = threadIdx.x;
    ushort2 u = *(const ushort2*)&x[t * 2];
    float a = b2f(u.x), b = b2f(u.y);
    float m = blk_max(fmaxf(a, b));
    a = __expf(a - m); b = __expf(b - m);
    float s = blk_sum(a + b);
    float inv = 1.f / s;
    u.x = f2b(a * inv); u.y = f2b(b * inv);
    *(ushort2*)&x[t * 2] = u;
}

// ---------------- LN + front-pad -> bf16 ----------------
__global__ __launch_bounds__(256)
void ln_pad(const float* __restrict__ H, const float* __restrict__ g,
            const float* __restrict__ b, ushort* __restrict__ X)
{
    int row = blockIdx.x, t = threadIdx.x;
    ushort* o = X + (long long)row * DIM;
    if (row < PAD) {
        #pragma unroll
        for (int i = 0; i < 4; i++) o[t + i * 256] = 0;
        return;
    }
    const float* x = H + (long long)(row - PAD) * DIM;
    float r[4]; float s = 0.f;
    #pragma unroll
    for (int i = 0; i < 4; i++) { r[i] = x[t + i * 256]; s += r[i]; }
    float mu = blk_sum(s) * (1.f / DIM);
    float v = 0.f;
    #pragma unroll
    for (int i = 0; i < 4; i++) { float d = r[i] - mu; v += d * d; }
    float var = blk_sum(v) * (1.f / DIM);
    float rs = rsqrtf(var + 1e-5f);
    #pragma unroll
    for (int i = 0; i < 4; i++) { int c = t + i * 256; o[c] = f2b((r[i] - mu) * rs * g[c] + b[c]); }
}

// ---------------- landmarks ----------------
__global__ __launch_bounds__(128)
void landmarks(const ushort* __restrict__ QKVb, ushort* __restrict__ QL, ushort* __restrict__ KL)
{
    int L = blockIdx.x, h = blockIdx.y, d = threadIdx.x;
    float sq = 0.f, sk = 0.f;
    #pragma unroll
    for (int j = 0; j < LSUB; j++) {
        const ushort* p = QKVb + (long long)(L * LSUB + j) * 3072 + h * DHEAD + d;
        sq += b2f(p[0]);
        sk += b2f(p[1024]);
    }
    QL[(long long)(h * LMK + L) * DHEAD + d] = f2b(sq * (1.f / LSUB));
    KL[(long long)(h * LMK + L) * DHEAD + d] = f2b(sk * (1.f / LSUB));
}

// ---------------- V transpose -> bf16 VT[h][d][i] ----------------
__global__ void vtrans(const ushort* __restrict__ Q, ushort* __restrict__ VT)
{
    __shared__ ushort tile[32][33];
    int h = blockIdx.z, i0 = blockIdx.x * 32, d0 = blockIdx.y * 32;
    int tx = threadIdx.x, ty = threadIdx.y;
    for (int yy = ty; yy < 32; yy += 8)
        tile[yy][tx] = Q[(long long)(i0 + yy) * 3072 + 2048 + h * 128 + d0 + tx];
    __syncthreads();
    for (int yy = ty; yy < 32; yy += 8)
        VT[((long long)h * 128 + d0 + yy) * 6144 + i0 + tx] = tile[tx][yy];
}

// ---------------- a2 column sums (rows of softmax sum to 1) ----------------
__global__ __launch_bounds__(256)
void a2_sums2(const float* __restrict__ A2, float* __restrict__ cols)
{
    int h = blockIdx.x, slice = blockIdx.y, t = threadIdx.x;
    const float* a = A2 + (long long)h * LMK * LMK + (long long)slice * 64 * LMK;
    float s0 = 0.f, s1 = 0.f;
    #pragma unroll 4
    for (int i = 0; i < 64; i++) {
        s0 += a[(long long)i * LMK + t];
        s1 += a[(long long)i * LMK + t + 256];
    }
    atomicAdd(&cols[h * LMK + t], s0);
    atomicAdd(&cols[h * LMK + t + 256], s1);
}
__global__ __launch_bounds__(256)
void a2_scal2(const float* __restrict__ cols, float* __restrict__ scal)
{
    float mc = -1e30f;
    for (int i = threadIdx.x; i < HEADS * LMK; i += 256) mc = fmaxf(mc, cols[i]);
    mc = blk_max(mc);
    if (threadIdx.x == 0) scal[0] = 1.f / mc;   // max row sum == 1 (softmax)
}

// ---------------- z0/X prep: Xb = bf16(a2); Z0T = bf16(s*a2); Z0b = bf16(s*a2^T) ----------------
__global__ void z0_t(const float* __restrict__ A2, ushort* __restrict__ Xb,
                     ushort* __restrict__ Z0b, ushort* __restrict__ Z0T,
                     const float* __restrict__ scal)
{
    __shared__ float tile[32][33];
    int h = blockIdx.z;
    const float* a = A2 + (long long)h * LMK * LMK;
    float s = scal[0];
    int x0 = blockIdx.x * 32, y0 = blockIdx.y * 32;
    int tx = threadIdx.x, ty = threadIdx.y;
    long long hb = (long long)h * LMK * LMK;
    for (int yy = ty; yy < 32; yy += 8) {
        float v = a[(long long)(y0 + yy) * LMK + x0 + tx];
        tile[yy][tx] = v;
        Xb [hb + (long long)(y0 + yy) * LMK + x0 + tx] = f2b(v);
        Z0T[hb + (long long)(y0 + yy) * LMK + x0 + tx] = f2b(s * v);
    }
    __syncthreads();
    for (int yy = ty; yy < 32; yy += 8)
        Z0b[hb + (long long)(x0 + yy) * LMK + y0 + tx] = f2b(s * tile[tx][yy]);
}

// ---------------- MoE ----------------
__global__ __launch_bounds__(256)
void moe_combine(const float* __restrict__ X, const float* __restrict__ wg,
                 const float* __restrict__ EO, const float* __restrict__ eb,
                 float* __restrict__ H)
{
    int i = blockIdx.x, t = threadIdx.x;
    const float* x = X + (long long)i * INDIM;
    float g0 = 0.f, g1 = 0.f, g2 = 0.f;
    for (int f = t; f < INDIM; f += 256) {
        float xv = x[f];
        const float* w = wg + f * 3;
        g0 += xv * w[0]; g1 += xv * w[1]; g2 += xv * w[2];
    }
    g0 = blk_sum(g0); g1 = blk_sum(g1); g2 = blk_sum(g2);
    float m = fmaxf(g0, fmaxf(g1, g2));
    float e0 = __expf(g0 - m), e1 = __expf(g1 - m), e2 = __expf(g2 - m);
    float inv = 1.f / (e0 + e1 + e2);
    e0 *= inv; e1 *= inv; e2 *= inv;
    const float* eo = EO + (long long)i * 3072;
    for (int o = t; o < DIM; o += 256) {
        float v0 = fmaxf(eo[o]        + eb[o],        0.f);
        float v1 = fmaxf(eo[1024 + o] + eb[1024 + o], 0.f);
        float v2 = fmaxf(eo[2048 + o] + eb[2048 + o], 0.f);
        float r = e0 * v0 + e1 * v1 + e2 * v2;
        H[(long long)(1 + i) * DIM + o] = r;
        if (i < 84) H[(long long)(6001 + i) * DIM + o] = r;
    }
}

__global__ void cls_copy(const float* __restrict__ c, float* __restrict__ H)
{
    for (int i = threadIdx.x; i < DIM; i += 256) H[i] = c[i];
}

// ---------------- res conv: Ob = bf16(O + depthwise33(V)) ----------------
__global__ __launch_bounds__(256)
void resconv(const ushort* __restrict__ QKVb, const float* __restrict__ rw,
             const float* __restrict__ O, ushort* __restrict__ Ob)
{
    long long idx = (long long)blockIdx.x * 256 + threadIdx.x;
    int c = (int)(idx & 1023);
    long long i = idx >> 10;
    int h = c >> 7;
    float acc = O[idx];
    #pragma unroll
    for (int t = 0; t < 33; t++) {
        long long r = i + t - 16;
        if (r >= 0 && r < NPL) acc += rw[h * 33 + t] * b2f(QKVb[r * 3072 + 2048 + c]);
    }
    Ob[idx] = f2b(acc);
}

// ---------------- PPEG ----------------
__global__ void h2f(const float* __restrict__ H, float* __restrict__ F)
{
    __shared__ float tile[32][33];
    int p0 = blockIdx.x * 32, c0 = blockIdx.y * 32;
    int tx = threadIdx.x, ty = threadIdx.y;
    for (int yy = ty; yy < 32; yy += 8) {
        int p = p0 + yy;
        if (p < HW * HW) tile[yy][tx] = H[(long long)(1 + p) * DIM + c0 + tx];
    }
    __syncthreads();
    for (int yy = ty; yy < 32; yy += 8) {
        int p = p0 + tx, c = c0 + yy;
        if (p < HW * HW) F[(long long)c * (HW * HW) + p] = tile[tx][yy];
    }
}
__global__ void f2h(const float* __restrict__ F2, float* __restrict__ H)
{
    __shared__ float tile[32][33];
    int c0 = blockIdx.x * 32, p0 = blockIdx.y * 32;
    int tx = threadIdx.x, ty = threadIdx.y;
    for (int yy = ty; yy < 32; yy += 8) {
        int p = p0 + tx;
        if (p < HW * HW) tile[yy][tx] = F2[(long long)(c0 + yy) * (HW * HW) + p];
    }
    __syncthreads();
    for (int yy = ty; yy < 32; yy += 8) {
        int p = p0 + yy;
        if (p < HW * HW) H[(long long)(1 + p) * DIM + c0 + tx] = tile[tx][yy];
    }
}
// merged 7x7 (+5x5 +3x3 +identity) single-pass depthwise conv
__global__ __launch_bounds__(256)
void ppeg_conv2(const float* __restrict__ F,
                const float* __restrict__ w7, const float* __restrict__ b7,
                const float* __restrict__ w5, const float* __restrict__ b5,
                const float* __restrict__ w3, const float* __restrict__ b3,
                float* __restrict__ F2)
{
    int c = blockIdx.x, t = threadIdx.x;
    __shared__ float plane[HW * HW];
    __shared__ float wm[49];
    for (int p = t; p < HW * HW; p += 256) plane[p] = F[(long long)c * (HW * HW) + p];
    if (t < 49) {
        int ky = t / 7 - 3, kx = t % 7 - 3;
        float w = w7[(long long)c * 49 + t];
        if (ky >= -2 && ky <= 2 && kx >= -2 && kx <= 2) w += w5[(long long)c * 25 + (ky + 2) * 5 + (kx + 2)];
        if (ky >= -1 && ky <= 1 && kx >= -1 && kx <= 1) w += w3[(long long)c * 9 + (ky + 1) * 3 + (kx + 1)];
        if (t == 24) w += 1.0f;   // identity term
        wm[t] = w;
    }
    __syncthreads();
    float bsum = b7[c] + b5[c] + b3[c];
    for (int p = t; p < HW * HW; p += 256) {
        int y = p / HW, x = p - y * HW;
        float acc = bsum;
        if (y >= 3 && y < HW - 3 && x >= 3 && x < HW - 3) {
            const float* base = &plane[p];
            #pragma unroll
            for (int ky = -3; ky <= 3; ky++)
                #pragma unroll
                for (int kx = -3; kx <= 3; kx++)
                    acc += wm[(ky + 3) * 7 + kx + 3] * base[ky * HW + kx];
        } else {
            for (int ky = -3; ky <= 3; ky++) {
                int yy = y + ky; if ((unsigned)yy >= (unsigned)HW) continue;
                for (int kx = -3; kx <= 3; kx++) {
                    int xx = x + kx; if ((unsigned)xx >= (unsigned)HW) continue;
                    acc += wm[(ky + 3) * 7 + kx + 3] * plane[yy * HW + xx];
                }
            }
        }
        F2[(long long)c * (HW * HW) + p] = acc;
    }
}

// ---------------- final head ----------------
__global__ __launch_bounds__(256)
void head_k(const float* __restrict__ H, const float* __restrict__ g, const float* __restrict__ b,
            const float* __restrict__ fw, const float* __restrict__ fb, float* __restrict__ out)
{
    int t = threadIdx.x;
    float r[4]; float s = 0.f;
    #pragma unroll
    for (int i = 0; i < 4; i++) { r[i] = H[t + i * 256]; s += r[i]; }
    float mu = blk_sum(s) * (1.f / DIM);
    float v = 0.f;
    #pragma unroll
    for (int i = 0; i < 4; i++) { float d = r[i] - mu; v += d * d; }
    float var = blk_sum(v) * (1.f / DIM);
    float rs = rsqrtf(var + 1e-5f);
    float d0 = 0.f, d1 = 0.f;
    #pragma unroll
    for (int i = 0; i < 4; i++) {
        int c = t + i * 256;
        float hv = (r[i] - mu) * rs * g[c] + b[c];
        d0 += hv * fw[c];
        d1 += hv * fw[DIM + c];
    }
    d0 = blk_sum(d0); d1 = blk_sum(d1);
    if (t == 0) {
        float l0 = d0 + fb[0], l1 = d1 + fb[1];
        float m = fmaxf(l0, l1);
        float e0 = __expf(l0 - m), e1 = __expf(l1 - m);
        float inv = 1.f / (e0 + e1);
        out[0] = l0; out[1] = l1;
        out[2] = e0 * inv; out[3] = e1 * inv;
        out[4] = (l1 > l0) ? 1.0f : 0.0f;
    }
}

// ---------------- host ----------------
extern "C" void kernel_launch(void* const* d_in, const int* in_sizes, int n_in,
                              void* d_out, int out_size, void* d_ws, size_t ws_size,
                              hipStream_t stream)
{
    const float* data     = (const float*)d_in[0];
    const float* w_gate   = (const float*)d_in[1];
    const float* expert_w = (const float*)d_in[2];
    const float* expert_b = (const float*)d_in[3];
    const float* cls_tok  = (const float*)d_in[4];
    const float* ln_g[2]  = {(const float*)d_in[5],  (const float*)d_in[11]};
    const float* ln_b[2]  = {(const float*)d_in[6],  (const float*)d_in[12]};
    const float* qkv_w[2] = {(const float*)d_in[7],  (const float*)d_in[13]};
    const float* out_w[2] = {(const float*)d_in[8],  (const float*)d_in[14]};
    const float* out_b[2] = {(const float*)d_in[9],  (const float*)d_in[15]};
    const float* res_w[2] = {(const float*)d_in[10], (const float*)d_in[16]};
    const float* pw7 = (const float*)d_in[17]; const float* pb7 = (const float*)d_in[18];
    const float* pw5 = (const float*)d_in[19]; const float* pb5 = (const float*)d_in[20];
    const float* pw3 = (const float*)d_in[21]; const float* pb3 = (const float*)d_in[22];
    const float* nf_g = (const float*)d_in[23]; const float* nf_b = (const float*)d_in[24];
    const float* fc2w = (const float*)d_in[25]; const float* fc2b = (const float*)d_in[26];

    float*  ws    = (float*)d_ws;
    float*  H     = ws + OFF_H;
    ushort* LNXb  = (ushort*)(ws + OFF_LNXO);
    float*  O     = ws + OFF_LNXO;
    ushort* QKVb  = (ushort*)(ws + OFF_QKVB);
    float*  EO    = ws + OFF_QKVB;            // spills into S pre-stage (ok)
    ushort* S     = (ushort*)(ws + OFF_S);
    ushort* Ob    = (ushort*)(ws + OFF_S);    // bf16 attn-out (after S dead)
    ushort* VT    = (ushort*)(ws + OFF_VT);
    ushort* QL    = (ushort*)(ws + OFF_QL);
    ushort* KL    = (ushort*)(ws + OFF_KL);
    float*  A2F   = ws + OFF_A2F;
    ushort* BVTb  = (ushort*)(ws + OFF_BVTB);
    ushort* Xb    = (ushort*)(ws + OFF_XB);
    ushort* XZB   = (ushort*)(ws + OFF_XZB);
    ushort* XZT7  = (ushort*)(ws + OFF_XZT7);
    ushort* PT15  = (ushort*)(ws + OFF_PT15);
    ushort* QT13  = (ushort*)(ws + OFF_QT13);
    ushort* ZB[2] = {(ushort*)(ws + OFF_ZB0), (ushort*)(ws + OFF_ZB1)};
    ushort* ZT[2] = {(ushort*)(ws + OFF_ZT0), (ushort*)(ws + OFF_ZT1)};
    float*  BVT   = ws + OFF_BVT;
    ushort* ZBT   = (ushort*)(ws + OFF_ZBT);
    ushort* QWB   = (ushort*)(ws + OFF_QWB);
    ushort* OWB   = (ushort*)(ws + OFF_OWB);
    ushort* DATAB = (ushort*)(ws + OFF_DATAB);
    ushort* EWB   = (ushort*)(ws + OFF_EWB);
    float*  COLS  = ws + OFF_COLS;
    float*  SCAL  = ws + OFF_SCAL;

    const long long HSB = (long long)LMK * DHEAD;   // 65536
    const long long A2S = (long long)LMK * LMK;     // 262144
    const long long SS  = (long long)LMK * NPL;     // 3145728

    // ---- MoE ----
    cvt_bf16<<<4500, 256, 0, stream>>>(data, DATAB, (long long)NTOK * INDIM);
    cvt_bf16<<<2304, 256, 0, stream>>>(expert_w, EWB, 3072LL * INDIM);
    mg<0><<<dim3(24,47,1),256,0,stream>>>(DATAB,INDIM,0, EWB,INDIM,0, EO,3072,0,
        nullptr,0,0, NTOK,INDIM, nullptr, 1.f,0.f,0.f,1);
    moe_combine<<<NTOK,256,0,stream>>>(data, w_gate, EO, expert_b, H);
    cls_copy<<<1,256,0,stream>>>(cls_tok, H);

    for (int stage = 0; stage < 2; stage++) {
        cvt_bf16<<<1536, 256, 0, stream>>>(qkv_w[stage], QWB, 3072LL * DIM);
        cvt_bf16<<<512, 256, 0, stream>>>(out_w[stage], OWB, (long long)DIM * DIM);
        ln_pad<<<NPL,256,0,stream>>>(H, ln_g[stage], ln_b[stage], LNXb);
        // QKVb = LNX @ qkv_w^T (bf16 out, q scaled)
        mg<1><<<dim3(24,48,1),256,0,stream>>>(LNXb,DIM,0, QWB,DIM,0, QKVb,3072,0,
            nullptr,0,0, NPL,DIM, nullptr, 1.f,0.f,0.f,1);
        landmarks<<<dim3(LMK,HEADS),128,0,stream>>>(QKVb, QL, KL);
        vtrans<<<dim3(192,4,8),dim3(32,8),0,stream>>>(QKVb, VT);
        // a2 = softmax(ql @ kl^T) f32
        mg<0><<<dim3(4,4,8),256,0,stream>>>(QL,DHEAD,HSB, KL,DHEAD,HSB, A2F,LMK,A2S,
            nullptr,0,0, LMK,DHEAD, nullptr, 1.f,0.f,0.f,1);
        softmax_rows<2><<<HEADS*LMK,256,0,stream>>>(A2F, LMK);
        hipMemsetAsync(COLS, 0, HEADS * LMK * sizeof(float), stream);
        a2_sums2<<<dim3(HEADS,8),256,0,stream>>>(A2F, COLS);
        a2_scal2<<<1,256,0,stream>>>(COLS, SCAL);
        z0_t<<<dim3(16,16,8),dim3(32,8),0,stream>>>(A2F, Xb, ZB[0], ZT[0], SCAL);
        // Newton-Schulz: 6 iterations, all bf16 MFMA with transpose-affine epilogues
        int cur = 0;
        for (int it = 0; it < 6; it++) {
            // G1: XZ = X @ z ; out: XZB (bf16), XZT7 = 7I - XZ^T
            mg<4><<<dim3(4,4,8),256,0,stream>>>(Xb,LMK,A2S, ZT[cur],LMK,A2S, XZB,LMK,A2S,
                XZT7,LMK,A2S, LMK,LMK, nullptr, 1.f, 7.f, -1.f, 1);
            // G2: P = XZ @ (7I - XZ) ; out: PT15 = 15I - P^T
            mg<5><<<dim3(4,4,8),256,0,stream>>>(XZB,LMK,A2S, XZT7,LMK,A2S, nullptr,0,0,
                PT15,LMK,A2S, LMK,LMK, nullptr, 1.f, 15.f, -1.f, 1);
            // G3: Q = XZ @ (15I - P) ; out: QT13 = 13I - Q^T
            mg<5><<<dim3(4,4,8),256,0,stream>>>(XZB,LMK,A2S, PT15,LMK,A2S, nullptr,0,0,
                QT13,LMK,A2S, LMK,LMK, nullptr, 1.f, 13.f, -1.f, 1);
            // G4: z' = 0.25 z @ (13I - Q)
            if (it < 5)
                mg<4><<<dim3(4,4,8),256,0,stream>>>(ZB[cur],LMK,A2S, QT13,LMK,A2S, ZB[1-cur],LMK,A2S,
                    ZT[1-cur],LMK,A2S, LMK,LMK, nullptr, 0.25f, 0.f, 1.f, 1);
            else
                mg<2><<<dim3(4,4,8),256,0,stream>>>(ZB[cur],LMK,A2S, QT13,LMK,A2S, ZB[1-cur],LMK,A2S,
                    nullptr,0,0, LMK,LMK, nullptr, 0.25f, 0.f, 1.f, 1);
            cur = 1 - cur;
        }
        ushort* Z6 = ZB[cur];
        // a3 = softmax(ql @ k^T) -> S bf16
        mg<2><<<dim3(48,4,8),256,0,stream>>>(QL,DHEAD,HSB, QKVb+1024,3072,128, S,NPL,SS,
            nullptr,0,0, LMK,DHEAD, nullptr, 1.f,0.f,0.f,1);
        softmax_b6144<<<HEADS*LMK,256,0,stream>>>(S);
        // bvT[d][l] = (a3 @ v)^T  (split-K 8, transposed atomic f32)
        hipMemsetAsync(BVT, 0, (size_t)HEADS * LMK * DHEAD * 4, stream);
        mg<9><<<dim3(1,4,64),256,0,stream>>>(S,NPL,SS, VT,NPL,(long long)DHEAD*NPL, BVT,LMK,HSB,
            nullptr,0,0, LMK,NPL, nullptr, 1.f,0.f,0.f, 8);
        cvt_bf16<<<256,256,0,stream>>>(BVT, BVTb, (long long)HEADS * LMK * DHEAD);
        // ZBT[d][l] = sum_k bvT[d][k] * z6[l][k]  (bf16 MFMA)
        mg<2><<<dim3(4,1,8),256,0,stream>>>(BVTb,LMK,HSB, Z6,LMK,A2S, ZBT,LMK,HSB,
            nullptr,0,0, DHEAD,LMK, nullptr, 1.f,0.f,0.f,1);
        // a1 = softmax(q @ kl^T) -> S bf16
        mg<2><<<dim3(4,48,8),256,0,stream>>>(QKVb,3072,128, KL,DHEAD,HSB, S,LMK,SS,
            nullptr,0,0, NPL,DHEAD, nullptr, 1.f,0.f,0.f,1);
        softmax_b512<<<HEADS*NPL,256,0,stream>>>(S);
        // O = a1 @ zb (f32, per-head 128-col slabs)
        mg<0><<<dim3(1,48,8),256,0,stream>>>(S,LMK,SS, ZBT,LMK,HSB, O,DIM,128,
            nullptr,0,0, NPL,LMK, nullptr, 1.f,0.f,0.f,1);
        // Ob = bf16(O + res conv of v)
        resconv<<<(NPL*DIM)/256,256,0,stream>>>(QKVb, res_w[stage], O, Ob);
        // H += Ob @ out_w^T + out_b
        mg<3><<<dim3(8,48,1),256,0,stream>>>(Ob + (long long)PAD*DIM,DIM,0, OWB,DIM,0, H,DIM,0,
            nullptr,0,0, NH,DIM, out_b[stage], 1.f,0.f,0.f,1);
        if (stage == 0) {
            float* F  = ws + OFF_QKVB;
            float* F2 = F + 6230016LL;
            h2f<<<dim3(191,32),dim3(32,8),0,stream>>>(H, F);
            ppeg_conv2<<<DIM,256,0,stream>>>(F, pw7, pb7, pw5, pb5, pw3, pb3, F2);
            f2h<<<dim3(32,191),dim3(32,8),0,stream>>>(F2, H);
        }
    }

    head_k<<<1,256,0,stream>>>(H, nf_g, nf_b, fc2w, fc2b, (float*)d_out);
}

// Round 6
// 1972.525 us; speedup vs baseline: 5.8662x; 1.0803x over previous
//
#include <hip/hip_runtime.h>
#include <hip/hip_bf16.h>

// ---------------- constants ----------------
#define NTOK   6000
#define INDIM  1536
#define DIM    1024
#define NPL    6144
#define PAD    59
#define NH     6085
#define HEADS  8
#define DHEAD  128
#define LMK    512
#define LSUB   12
#define HW     78
#define QSCALE 0.08838834764831845f

// ---------------- ws layout (float-slot offsets) ----------------
#define OFF_H     0LL          // 6144*1024 f32
#define OFF_LNXO  6291456LL    // LNXb bf16 / O f32 alias
#define OFF_QKVB  12582912LL   // 6144*3072 bf16; EO bf16 + PPEG planes alias
#define OFF_PBV   22020096LL   // 8h*512*8c*128 f32 = 4194304
#define OFF_PM    26214400LL   // 32768
#define OFF_PL    26247168LL   // 32768
#define OFF_OB    26279936LL   // 6144*1024 bf16 = 3145728 slots
#define OFF_VT    34603008LL   // 8*128*6144 bf16
#define OFF_QL    37748736LL
#define OFF_KL    38010880LL
#define OFF_A2F   38273024LL   // 8*512*512 f32
#define OFF_BVTB  40370176LL   // 8*128*512 bf16
#define OFF_XB    42467328LL   // bf16 8*512*512 each below
#define OFF_XZB   43515904LL
#define OFF_XZT7  44564480LL
#define OFF_PT15  45613056LL
#define OFF_QT13  46661632LL
#define OFF_ZB0   47710208LL
#define OFF_ZT0   48758784LL
#define OFF_ZB1   49807360LL
#define OFF_ZT1   50855936LL
#define OFF_ZBT   52428800LL   // 8*128*512 bf16
#define OFF_QWB   52690944LL   // 3072*1024 bf16
#define OFF_OWB   54263808LL   // 1024*1024 bf16
#define OFF_COLS  54788096LL
#define OFF_SCAL  54796288LL
// transient aliases (dead before overlapping buffers are written)
#define OFF_DATAB 31457280LL   // 6000*1536 bf16 (pre-stage only)
#define OFF_EWB   36065280LL   // 3072*1536 bf16 (pre-stage only)

typedef __attribute__((ext_vector_type(8))) short s16x8;
typedef __attribute__((ext_vector_type(4))) float f32x4;

// ---------------- bf16 helpers ----------------
__device__ __forceinline__ ushort f2b(float f) {
    union { float f; unsigned u; } v; v.f = f;
    return (ushort)((v.u + 0x7FFF + ((v.u >> 16) & 1)) >> 16);
}
__device__ __forceinline__ float b2f(ushort h) {
    union { unsigned u; float f; } v; v.u = ((unsigned)h) << 16; return v.f;
}

// async global->LDS, 16 bytes per lane; lds ptr must be wave-uniform
__device__ __forceinline__ void gld16(const void* g, void* l) {
    __builtin_amdgcn_global_load_lds((const __attribute__((address_space(1))) void*)g,
                                     (__attribute__((address_space(3))) void*)l, 16, 0, 0);
}

// ---------------- reductions (blockDim.x == 256) ----------------
__device__ __forceinline__ float blk_sum(float v) {
    __shared__ float sb[4];
    #pragma unroll
    for (int o = 32; o > 0; o >>= 1) v += __shfl_down(v, o);
    int lane = threadIdx.x & 63, w = threadIdx.x >> 6;
    __syncthreads();
    if (lane == 0) sb[w] = v;
    __syncthreads();
    return sb[0] + sb[1] + sb[2] + sb[3];
}
__device__ __forceinline__ float blk_max(float v) {
    __shared__ float sb[4];
    #pragma unroll
    for (int o = 32; o > 0; o >>= 1) v = fmaxf(v, __shfl_down(v, o));
    int lane = threadIdx.x & 63, w = threadIdx.x >> 6;
    __syncthreads();
    if (lane == 0) sb[w] = v;
    __syncthreads();
    return fmaxf(fmaxf(sb[0], sb[1]), fmaxf(sb[2], sb[3]));
}

// ================= MFMA GEMM (bf16 x bf16), C = alpha * A @ B^T =================
// EPI: 0 f32 | 1 bf16 qkv-scale | 2 bf16 | 3 f32 += v+bias | 4 bf16 C + bf16 T^T affine | 5 T only
template<int EPI>
__global__ __launch_bounds__(256)
void mg(const ushort* __restrict__ A, int lda, long long sA,
        const ushort* __restrict__ B, int ldb, long long sB,
        void* __restrict__ Cp, int ldc, long long sC,
        void* __restrict__ Tp, int ldt, long long sT,
        int M, int K, const float* __restrict__ bias,
        float alpha, float tdelta, float tsign)
{
    __shared__ ushort As[4096];
    __shared__ ushort Bs[4096];
    const int t = threadIdx.x;
    const int z = blockIdx.z;
    const ushort* Ab = A + (long long)z * sA;
    const ushort* Bb = B + (long long)z * sB;
    const int row0 = blockIdx.y * 128, col0 = blockIdx.x * 128;
    const int w = t >> 6, lane = t & 63;
    const int l4 = lane >> 2, ls = (lane & 3) * 8;
    const int q0 = w, q1 = 4 + w;
    int ar0 = row0 + q0 * 16 + l4; if (ar0 >= M) ar0 = M - 1;
    int ar1 = row0 + q1 * 16 + l4; if (ar1 >= M) ar1 = M - 1;
    const int br0 = col0 + q0 * 16 + l4;
    const int br1 = col0 + q1 * 16 + l4;
    const ushort* ap0 = Ab + (long long)ar0 * lda + ls;
    const ushort* ap1 = Ab + (long long)ar1 * lda + ls;
    const ushort* bp0 = Bb + (long long)br0 * ldb + ls;
    const ushort* bp1 = Bb + (long long)br1 * ldb + ls;
    ushort* asl0 = &As[q0 * 512];
    ushort* asl1 = &As[q1 * 512];
    ushort* bsl0 = &Bs[q0 * 512];
    ushort* bsl1 = &Bs[q1 * 512];

    const int wr = (w >> 1) * 64, wc = (w & 1) * 64;
    const int fr = lane & 15, fo = (lane >> 4) * 8;

    f32x4 acc[4][4];
    #pragma unroll
    for (int a = 0; a < 4; a++)
        #pragma unroll
        for (int b = 0; b < 4; b++)
            acc[a][b] = (f32x4){0.f, 0.f, 0.f, 0.f};

    for (int kt = 0; kt < K; kt += 32) {
        gld16(ap0 + kt, asl0);
        gld16(ap1 + kt, asl1);
        gld16(bp0 + kt, bsl0);
        gld16(bp1 + kt, bsl1);
        __syncthreads();
        s16x8 af[4], bf[4];
        #pragma unroll
        for (int a = 0; a < 4; a++) af[a] = *(const s16x8*)&As[(wr + a * 16 + fr) * 32 + fo];
        #pragma unroll
        for (int b = 0; b < 4; b++) bf[b] = *(const s16x8*)&Bs[(wc + b * 16 + fr) * 32 + fo];
        #pragma unroll
        for (int a = 0; a < 4; a++)
            #pragma unroll
            for (int b = 0; b < 4; b++)
                acc[a][b] = __builtin_amdgcn_mfma_f32_16x16x32_bf16(af[a], bf[b], acc[a][b], 0, 0, 0);
        __syncthreads();
    }

    const int er0 = row0 + wr + ((lane >> 4) << 2);
    const int ec0 = col0 + wc + fr;
    #pragma unroll
    for (int a = 0; a < 4; a++) {
        #pragma unroll
        for (int j = 0; j < 4; j++) {
            int r = er0 + a * 16 + j;
            if (r >= M) continue;
            #pragma unroll
            for (int b = 0; b < 4; b++) {
                int c = ec0 + b * 16;
                float v = alpha * acc[a][b][j];
                long long ci = z * sC + (long long)r * ldc + c;
                if constexpr (EPI == 0) ((float*)Cp)[ci] = v;
                else if constexpr (EPI == 1) ((ushort*)Cp)[ci] = f2b(c < 1024 ? v * QSCALE : v);
                else if constexpr (EPI == 2) ((ushort*)Cp)[ci] = f2b(v);
                else if constexpr (EPI == 3) ((float*)Cp)[ci] += v + bias[c];
                else {
                    ushort tv = f2b((r == c ? tdelta : 0.f) + tsign * v);
                    long long ti = z * sT + (long long)c * ldt + r;
                    if constexpr (EPI == 4) { ((ushort*)Cp)[ci] = f2b(v); ((ushort*)Tp)[ti] = tv; }
                    else { ((ushort*)Tp)[ti] = tv; }  // 5
                }
            }
        }
    }
}

// ================= fused flash attention =================
// out = softmax(Q @ K^T) @ Vt^T  per head; KV chunks of 64, d = 128.
// MODE 0: final output to O f32 (cols h*128..); MODE 1: partial (acc,m,l) per kv-split chunk.
template<int MODE>
__global__ __launch_bounds__(256)
void flash(const ushort* __restrict__ Qp, int ldq, long long sQh,
           const ushort* __restrict__ Kp, int ldk, long long sKh,
           const ushort* __restrict__ Vp, int ldv, long long sVh,
           float* __restrict__ Op, float* __restrict__ Pm, float* __restrict__ Pl,
           int nkv, int kvspan)
{
    __shared__ ushort Qs[16384];   // 4 subtiles [128][32]
    __shared__ ushort Zs[8192];    // 2 subtiles [128][32] (Vt chunk)
    __shared__ ushort KPs[8192];   // 4 subtiles [64][32] (K chunk); aliased by P [128][64] swizzled
    ushort* Ps = KPs;
    const int t = threadIdx.x;
    const int h = blockIdx.z;
    const int q0 = blockIdx.x * 128;
    const int kvbase = blockIdx.y * kvspan;
    const ushort* Qb = Qp + (long long)h * sQh;
    const ushort* Kb = Kp + (long long)h * sKh;
    const ushort* Vb = Vp + (long long)h * sVh;
    const int w = t >> 6, lane = t & 63;
    const int sr = lane >> 2, sc2 = (lane & 3) * 8;
    const int fr = lane & 15, fo = (lane >> 4) * 8;
    const int jr = (lane >> 4) * 4;

    // stage Q once: 4 subtiles x 2 row-halves
    #pragma unroll
    for (int s = 0; s < 4; s++)
        #pragma unroll
        for (int r0 = 0; r0 < 128; r0 += 64)
            gld16(Qb + (long long)(q0 + r0 + w * 16 + sr) * ldq + s * 32 + sc2,
                  &Qs[s * 4096 + (r0 + w * 16) * 32]);

    f32x4 oa[2][8];
    float mold[2][4], lrun[2][4];
    #pragma unroll
    for (int fi = 0; fi < 2; fi++) {
        #pragma unroll
        for (int fj = 0; fj < 8; fj++) oa[fi][fj] = (f32x4){0.f,0.f,0.f,0.f};
        #pragma unroll
        for (int j = 0; j < 4; j++) { mold[fi][j] = -1e30f; lrun[fi][j] = 0.f; }
    }

    for (int c = 0; c < nkv; c++) {
        int kvp = kvbase + c * 64;
        // stage K chunk (4 subtiles [64][32]) and Vt chunk (2 subtiles [128][32])
        #pragma unroll
        for (int s = 0; s < 4; s++)
            gld16(Kb + (long long)(kvp + w * 16 + sr) * ldk + s * 32 + sc2,
                  &KPs[s * 2048 + (w * 16) * 32]);
        #pragma unroll
        for (int s = 0; s < 2; s++)
            #pragma unroll
            for (int r0 = 0; r0 < 128; r0 += 64)
                gld16(Vb + (long long)(r0 + w * 16 + sr) * ldv + kvp + s * 32 + sc2,
                      &Zs[s * 4096 + (r0 + w * 16) * 32]);
        __syncthreads();   // staging complete

        // QK^T: S[128 q][64 kv], wave w owns rows w*32..+31
        f32x4 acc[2][4];
        #pragma unroll
        for (int fi = 0; fi < 2; fi++)
            #pragma unroll
            for (int fj = 0; fj < 4; fj++) acc[fi][fj] = (f32x4){0.f,0.f,0.f,0.f};
        #pragma unroll
        for (int ks = 0; ks < 4; ks++) {
            s16x8 qa[2], kb[4];
            #pragma unroll
            for (int fi = 0; fi < 2; fi++)
                qa[fi] = *(const s16x8*)&Qs[ks * 4096 + (w * 32 + fi * 16 + fr) * 32 + fo];
            #pragma unroll
            for (int fj = 0; fj < 4; fj++)
                kb[fj] = *(const s16x8*)&KPs[ks * 2048 + (fj * 16 + fr) * 32 + fo];
            #pragma unroll
            for (int fi = 0; fi < 2; fi++)
                #pragma unroll
                for (int fj = 0; fj < 4; fj++)
                    acc[fi][fj] = __builtin_amdgcn_mfma_f32_16x16x32_bf16(qa[fi], kb[fj], acc[fi][fj], 0, 0, 0);
        }

        // online softmax (rows wave-local; cols = 16 lanes x 4 frags)
        float rs[2][4];
        #pragma unroll
        for (int fi = 0; fi < 2; fi++) {
            #pragma unroll
            for (int j = 0; j < 4; j++) {
                float mx = acc[fi][0][j];
                #pragma unroll
                for (int fj = 1; fj < 4; fj++) mx = fmaxf(mx, acc[fi][fj][j]);
                mx = fmaxf(mx, __shfl_xor(mx, 1));
                mx = fmaxf(mx, __shfl_xor(mx, 2));
                mx = fmaxf(mx, __shfl_xor(mx, 4));
                mx = fmaxf(mx, __shfl_xor(mx, 8));
                float mn = fmaxf(mold[fi][j], mx);
                float scl = __expf(mold[fi][j] - mn);
                mold[fi][j] = mn;
                lrun[fi][j] *= scl;
                #pragma unroll
                for (int fj = 0; fj < 8; fj++) oa[fi][fj][j] *= scl;
                float r = 0.f;
                #pragma unroll
                for (int fj = 0; fj < 4; fj++) {
                    float p = __expf(acc[fi][fj][j] - mn);
                    acc[fi][fj][j] = p;
                    r += p;
                }
                r += __shfl_xor(r, 1);
                r += __shfl_xor(r, 2);
                r += __shfl_xor(r, 4);
                r += __shfl_xor(r, 8);
                rs[fi][j] = r;
            }
        }
        __syncthreads();   // all waves done reading KPs
        // write P (bf16) into swizzled [128][64] tile aliasing KPs
        #pragma unroll
        for (int fi = 0; fi < 2; fi++)
            #pragma unroll
            for (int j = 0; j < 4; j++) {
                int row = w * 32 + fi * 16 + jr + j;
                lrun[fi][j] += rs[fi][j];
                #pragma unroll
                for (int fj = 0; fj < 4; fj++) {
                    int idx = (row * 64 + fj * 16 + fr) ^ ((row & 7) << 3);
                    Ps[idx] = f2b(acc[fi][fj][j]);
                }
            }
        __syncthreads();   // P visible

        // PV: oa += P @ Vt^T
        #pragma unroll
        for (int ks2 = 0; ks2 < 2; ks2++) {
            s16x8 pa[2], zb[8];
            #pragma unroll
            for (int fi = 0; fi < 2; fi++) {
                int row = w * 32 + fi * 16 + fr;
                int idx = (row * 64 + ks2 * 32 + fo) ^ ((row & 7) << 3);
                pa[fi] = *(const s16x8*)&Ps[idx];
            }
            #pragma unroll
            for (int fj = 0; fj < 8; fj++)
                zb[fj] = *(const s16x8*)&Zs[ks2 * 4096 + (fj * 16 + fr) * 32 + fo];
            #pragma unroll
            for (int fi = 0; fi < 2; fi++)
                #pragma unroll
                for (int fj = 0; fj < 8; fj++)
                    oa[fi][fj] = __builtin_amdgcn_mfma_f32_16x16x32_bf16(pa[fi], zb[fj], oa[fi][fj], 0, 0, 0);
        }
        __syncthreads();   // done with Ps/Zs before next stage
    }

    // epilogue
    #pragma unroll
    for (int fi = 0; fi < 2; fi++)
        #pragma unroll
        for (int j = 0; j < 4; j++) {
            int row = w * 32 + fi * 16 + jr + j;
            if constexpr (MODE == 0) {
                float inv = 1.f / lrun[fi][j];
                #pragma unroll
                for (int fj = 0; fj < 8; fj++)
                    Op[(long long)(q0 + row) * DIM + h * 128 + fj * 16 + fr] = oa[fi][fj][j] * inv;
            } else {
                long long rb = (((long long)h * 512 + q0 + row) * 8 + blockIdx.y) * 128;
                #pragma unroll
                for (int fj = 0; fj < 8; fj++)
                    Op[rb + fj * 16 + fr] = oa[fi][fj][j];
                if (fr == 0) {
                    long long si = ((long long)h * 512 + q0 + row) * 8 + blockIdx.y;
                    Pm[si] = mold[fi][j];
                    Pl[si] = lrun[fi][j];
                }
            }
        }
}

// combine kv-split partials -> bvT bf16 [h][d][l]
__global__ __launch_bounds__(256)
void bv_combine(const float* __restrict__ PBV, const float* __restrict__ Pm,
                const float* __restrict__ Pl, ushort* __restrict__ BVTb)
{
    __shared__ float T[32][129];
    __shared__ float wc8[32][8], invL[32];
    int t = threadIdx.x;
    int h = blockIdx.y, l0 = blockIdx.x * 32;
    if (t < 32) {
        long long base = ((long long)h * 512 + l0 + t) * 8;
        float m = -1e30f;
        float mv[8], lv[8];
        #pragma unroll
        for (int c = 0; c < 8; c++) { mv[c] = Pm[base + c]; lv[c] = Pl[base + c]; m = fmaxf(m, mv[c]); }
        float L = 0.f;
        #pragma unroll
        for (int c = 0; c < 8; c++) { float wv = __expf(mv[c] - m); wc8[t][c] = wv; L += wv * lv[c]; }
        invL[t] = 1.f / L;
    }
    __syncthreads();
    int l = t >> 3, dg = t & 7;
    long long rbase = ((long long)h * 512 + l0 + l) * 8 * 128;
    #pragma unroll
    for (int dd = 0; dd < 16; dd++) {
        int d = dg * 16 + dd;
        float s = 0.f;
        #pragma unroll
        for (int c = 0; c < 8; c++) s += wc8[l][c] * PBV[rbase + c * 128 + d];
        T[l][d] = s * invL[l];
    }
    __syncthreads();
    int d = t >> 1, half = t & 1;
    #pragma unroll
    for (int lc = 0; lc < 16; lc++) {
        int l2 = half * 16 + lc;
        BVTb[(long long)h * 65536 + (long long)d * 512 + l0 + l2] = f2b(T[l2][d]);
    }
}

// ---------------- f32 -> bf16 convert ----------------
__global__ __launch_bounds__(256)
void cvt_bf16(const float* __restrict__ x, ushort* __restrict__ y, long long n)
{
    long long i = ((long long)blockIdx.x * 256 + threadIdx.x) * 8;
    if (i >= n) return;
    float4 a = *(const float4*)(x + i), b = *(const float4*)(x + i + 4);
    ushort4 u0 = {f2b(a.x), f2b(a.y), f2b(a.z), f2b(a.w)};
    ushort4 u1 = {f2b(b.x), f2b(b.y), f2b(b.z), f2b(b.w)};
    *(ushort4*)(y + i) = u0; *(ushort4*)(y + i + 4) = u1;
}

// ---------------- softmax fp32 rows (W = NIT*256) ----------------
template<int NIT>
__global__ __launch_bounds__(256)
void softmax_rows(float* __restrict__ X, int W)
{
    long long row = blockIdx.x;
    float* x = X + row * W;
    float r[NIT];
    float m = -1e30f;
    #pragma unroll
    for (int i = 0; i < NIT; i++) { r[i] = x[threadIdx.x + i * 256]; m = fmaxf(m, r[i]); }
    m = blk_max(m);
    float s = 0.f;
    #pragma unroll
    for (int i = 0; i < NIT; i++) { r[i] = __expf(r[i] - m); s += r[i]; }
    s = blk_sum(s);
    float inv = 1.f / s;
    #pragma unroll
    for (int i = 0; i < NIT; i++) x[threadIdx.x + i * 256] = r[i] * inv;
}

// ---------------- LN + front-pad -> bf16 ----------------
__global__ __launch_bounds__(256)
void ln_pad(const float* __restrict__ H, const float* __restrict__ g,
            const float* __restrict__ b, ushort* __restrict__ X)
{
    int row = blockIdx.x, t = threadIdx.x;
    ushort* o = X + (long long)row * DIM;
    if (row < PAD) {
        #pragma unroll
        for (int i = 0; i < 4; i++) o[t + i * 256] = 0;
        return;
    }
    const float* x = H + (long long)(row - PAD) * DIM;
    float r[4]; float s = 0.f;
    #pragma unroll
    for (int i = 0; i < 4; i++) { r[i] = x[t + i * 256]; s += r[i]; }
    float mu = blk_sum(s) * (1.f / DIM);
    float v = 0.f;
    #pragma unroll
    for (int i = 0; i < 4; i++) { float d = r[i] - mu; v += d * d; }
    float var = blk_sum(v) * (1.f / DIM);
    float rs = rsqrtf(var + 1e-5f);
    #pragma unroll
    for (int i = 0; i < 4; i++) { int c = t + i * 256; o[c] = f2b((r[i] - mu) * rs * g[c] + b[c]); }
}

// ---------------- landmarks ----------------
__global__ __launch_bounds__(128)
void landmarks(const ushort* __restrict__ QKVb, ushort* __restrict__ QL, ushort* __restrict__ KL)
{
    int L = blockIdx.x, h = blockIdx.y, d = threadIdx.x;
    float sq = 0.f, sk = 0.f;
    #pragma unroll
    for (int j = 0; j < LSUB; j++) {
        const ushort* p = QKVb + (long long)(L * LSUB + j) * 3072 + h * DHEAD + d;
        sq += b2f(p[0]);
        sk += b2f(p[1024]);
    }
    QL[(long long)(h * LMK + L) * DHEAD + d] = f2b(sq * (1.f / LSUB));
    KL[(long long)(h * LMK + L) * DHEAD + d] = f2b(sk * (1.f / LSUB));
}

// ---------------- V transpose -> bf16 VT[h][d][i] ----------------
__global__ void vtrans(const ushort* __restrict__ Q, ushort* __restrict__ VT)
{
    __shared__ ushort tile[32][33];
    int h = blockIdx.z, i0 = blockIdx.x * 32, d0 = blockIdx.y * 32;
    int tx = threadIdx.x, ty = threadIdx.y;
    for (int yy = ty; yy < 32; yy += 8)
        tile[yy][tx] = Q[(long long)(i0 + yy) * 3072 + 2048 + h * 128 + d0 + tx];
    __syncthreads();
    for (int yy = ty; yy < 32; yy += 8)
        VT[((long long)h * 128 + d0 + yy) * 6144 + i0 + tx] = tile[tx][yy];
}

// ---------------- a2 column sums ----------------
__global__ __launch_bounds__(256)
void a2_sums2(const float* __restrict__ A2, float* __restrict__ cols)
{
    int h = blockIdx.x, slice = blockIdx.y, t = threadIdx.x;
    const float* a = A2 + (long long)h * LMK * LMK + (long long)slice * 64 * LMK;
    float s0 = 0.f, s1 = 0.f;
    #pragma unroll 4
    for (int i = 0; i < 64; i++) {
        s0 += a[(long long)i * LMK + t];
        s1 += a[(long long)i * LMK + t + 256];
    }
    atomicAdd(&cols[h * LMK + t], s0);
    atomicAdd(&cols[h * LMK + t + 256], s1);
}
__global__ __launch_bounds__(256)
void a2_scal2(const float* __restrict__ cols, float* __restrict__ scal)
{
    float mc = -1e30f;
    for (int i = threadIdx.x; i < HEADS * LMK; i += 256) mc = fmaxf(mc, cols[i]);
    mc = blk_max(mc);
    if (threadIdx.x == 0) scal[0] = 1.f / mc;
}

// ---------------- z0/X prep ----------------
__global__ void z0_t(const float* __restrict__ A2, ushort* __restrict__ Xb,
                     ushort* __restrict__ Z0b, ushort* __restrict__ Z0T,
                     const float* __restrict__ scal)
{
    __shared__ float tile[32][33];
    int h = blockIdx.z;
    const float* a = A2 + (long long)h * LMK * LMK;
    float s = scal[0];
    int x0 = blockIdx.x * 32, y0 = blockIdx.y * 32;
    int tx = threadIdx.x, ty = threadIdx.y;
    long long hb = (long long)h * LMK * LMK;
    for (int yy = ty; yy < 32; yy += 8) {
        float v = a[(long long)(y0 + yy) * LMK + x0 + tx];
        tile[yy][tx] = v;
        Xb [hb + (long long)(y0 + yy) * LMK + x0 + tx] = f2b(v);
        Z0T[hb + (long long)(y0 + yy) * LMK + x0 + tx] = f2b(s * v);
    }
    __syncthreads();
    for (int yy = ty; yy < 32; yy += 8)
        Z0b[hb + (long long)(x0 + yy) * LMK + y0 + tx] = f2b(s * tile[tx][yy]);
}

// ---------------- MoE ----------------
__global__ __launch_bounds__(256)
void moe_combine(const float* __restrict__ X, const float* __restrict__ wg,
                 const ushort* __restrict__ EO, const float* __restrict__ eb,
                 float* __restrict__ H)
{
    int i = blockIdx.x, t = threadIdx.x;
    const float* x = X + (long long)i * INDIM;
    float g0 = 0.f, g1 = 0.f, g2 = 0.f;
    for (int f = t; f < INDIM; f += 256) {
        float xv = x[f];
        const float* w = wg + f * 3;
        g0 += xv * w[0]; g1 += xv * w[1]; g2 += xv * w[2];
    }
    g0 = blk_sum(g0); g1 = blk_sum(g1); g2 = blk_sum(g2);
    float m = fmaxf(g0, fmaxf(g1, g2));
    float e0 = __expf(g0 - m), e1 = __expf(g1 - m), e2 = __expf(g2 - m);
    float inv = 1.f / (e0 + e1 + e2);
    e0 *= inv; e1 *= inv; e2 *= inv;
    const ushort* eo = EO + (long long)i * 3072;
    for (int o = t; o < DIM; o += 256) {
        float v0 = fmaxf(b2f(eo[o])        + eb[o],        0.f);
        float v1 = fmaxf(b2f(eo[1024 + o]) + eb[1024 + o], 0.f);
        float v2 = fmaxf(b2f(eo[2048 + o]) + eb[2048 + o], 0.f);
        float r = e0 * v0 + e1 * v1 + e2 * v2;
        H[(long long)(1 + i) * DIM + o] = r;
        if (i < 84) H[(long long)(6001 + i) * DIM + o] = r;
    }
}

__global__ void cls_copy(const float* __restrict__ c, float* __restrict__ H)
{
    for (int i = threadIdx.x; i < DIM; i += 256) H[i] = c[i];
}

// ---------------- res conv: Ob = bf16(O + depthwise33(V)) ----------------
__global__ __launch_bounds__(256)
void resconv(const ushort* __restrict__ QKVb, const float* __restrict__ rw,
             const float* __restrict__ O, ushort* __restrict__ Ob)
{
    long long idx = (long long)blockIdx.x * 256 + threadIdx.x;
    int c = (int)(idx & 1023);
    long long i = idx >> 10;
    int h = c >> 7;
    float acc = O[idx];
    #pragma unroll
    for (int t = 0; t < 33; t++) {
        long long r = i + t - 16;
        if (r >= 0 && r < NPL) acc += rw[h * 33 + t] * b2f(QKVb[r * 3072 + 2048 + c]);
    }
    Ob[idx] = f2b(acc);
}

// ---------------- PPEG ----------------
__global__ void h2f(const float* __restrict__ H, float* __restrict__ F)
{
    __shared__ float tile[32][33];
    int p0 = blockIdx.x * 32, c0 = blockIdx.y * 32;
    int tx = threadIdx.x, ty = threadIdx.y;
    for (int yy = ty; yy < 32; yy += 8) {
        int p = p0 + yy;
        if (p < HW * HW) tile[yy][tx] = H[(long long)(1 + p) * DIM + c0 + tx];
    }
    __syncthreads();
    for (int yy = ty; yy < 32; yy += 8) {
        int p = p0 + tx, c = c0 + yy;
        if (p < HW * HW) F[(long long)c * (HW * HW) + p] = tile[tx][yy];
    }
}
__global__ void f2h(const float* __restrict__ F2, float* __restrict__ H)
{
    __shared__ float tile[32][33];
    int c0 = blockIdx.x * 32, p0 = blockIdx.y * 32;
    int tx = threadIdx.x, ty = threadIdx.y;
    for (int yy = ty; yy < 32; yy += 8) {
        int p = p0 + tx;
        if (p < HW * HW) tile[yy][tx] = F2[(long long)(c0 + yy) * (HW * HW) + p];
    }
    __syncthreads();
    for (int yy = ty; yy < 32; yy += 8) {
        int p = p0 + yy;
        if (p < HW * HW) H[(long long)(1 + p) * DIM + c0 + tx] = tile[tx][yy];
    }
}
__global__ __launch_bounds__(256)
void ppeg_conv2(const float* __restrict__ F,
                const float* __restrict__ w7, const float* __restrict__ b7,
                const float* __restrict__ w5, const float* __restrict__ b5,
                const float* __restrict__ w3, const float* __restrict__ b3,
                float* __restrict__ F2)
{
    int c = blockIdx.x, t = threadIdx.x;
    __shared__ float plane[HW * HW];
    __shared__ float wm[49];
    for (int p = t; p < HW * HW; p += 256) plane[p] = F[(long long)c * (HW * HW) + p];
    if (t < 49) {
        int ky = t / 7 - 3, kx = t % 7 - 3;
        float w = w7[(long long)c * 49 + t];
        if (ky >= -2 && ky <= 2 && kx >= -2 && kx <= 2) w += w5[(long long)c * 25 + (ky + 2) * 5 + (kx + 2)];
        if (ky >= -1 && ky <= 1 && kx >= -1 && kx <= 1) w += w3[(long long)c * 9 + (ky + 1) * 3 + (kx + 1)];
        if (t == 24) w += 1.0f;
        wm[t] = w;
    }
    __syncthreads();
    float bsum = b7[c] + b5[c] + b3[c];
    for (int p = t; p < HW * HW; p += 256) {
        int y = p / HW, x = p - y * HW;
        float acc = bsum;
        if (y >= 3 && y < HW - 3 && x >= 3 && x < HW - 3) {
            const float* base = &plane[p];
            #pragma unroll
            for (int ky = -3; ky <= 3; ky++)
                #pragma unroll
                for (int kx = -3; kx <= 3; kx++)
                    acc += wm[(ky + 3) * 7 + kx + 3] * base[ky * HW + kx];
        } else {
            for (int ky = -3; ky <= 3; ky++) {
                int yy = y + ky; if ((unsigned)yy >= (unsigned)HW) continue;
                for (int kx = -3; kx <= 3; kx++) {
                    int xx = x + kx; if ((unsigned)xx >= (unsigned)HW) continue;
                    acc += wm[(ky + 3) * 7 + kx + 3] * plane[yy * HW + xx];
                }
            }
        }
        F2[(long long)c * (HW * HW) + p] = acc;
    }
}

// ---------------- final head ----------------
__global__ __launch_bounds__(256)
void head_k(const float* __restrict__ H, const float* __restrict__ g, const float* __restrict__ b,
            const float* __restrict__ fw, const float* __restrict__ fb, float* __restrict__ out)
{
    int t = threadIdx.x;
    float r[4]; float s = 0.f;
    #pragma unroll
    for (int i = 0; i < 4; i++) { r[i] = H[t + i * 256]; s += r[i]; }
    float mu = blk_sum(s) * (1.f / DIM);
    float v = 0.f;
    #pragma unroll
    for (int i = 0; i < 4; i++) { float d = r[i] - mu; v += d * d; }
    float var = blk_sum(v) * (1.f / DIM);
    float rs = rsqrtf(var + 1e-5f);
    float d0 = 0.f, d1 = 0.f;
    #pragma unroll
    for (int i = 0; i < 4; i++) {
        int c = t + i * 256;
        float hv = (r[i] - mu) * rs * g[c] + b[c];
        d0 += hv * fw[c];
        d1 += hv * fw[DIM + c];
    }
    d0 = blk_sum(d0); d1 = blk_sum(d1);
    if (t == 0) {
        float l0 = d0 + fb[0], l1 = d1 + fb[1];
        float m = fmaxf(l0, l1);
        float e0 = __expf(l0 - m), e1 = __expf(l1 - m);
        float inv = 1.f / (e0 + e1);
        out[0] = l0; out[1] = l1;
        out[2] = e0 * inv; out[3] = e1 * inv;
        out[4] = (l1 > l0) ? 1.0f : 0.0f;
    }
}

// ---------------- host ----------------
extern "C" void kernel_launch(void* const* d_in, const int* in_sizes, int n_in,
                              void* d_out, int out_size, void* d_ws, size_t ws_size,
                              hipStream_t stream)
{
    const float* data     = (const float*)d_in[0];
    const float* w_gate   = (const float*)d_in[1];
    const float* expert_w = (const float*)d_in[2];
    const float* expert_b = (const float*)d_in[3];
    const float* cls_tok  = (const float*)d_in[4];
    const float* ln_g[2]  = {(const float*)d_in[5],  (const float*)d_in[11]};
    const float* ln_b[2]  = {(const float*)d_in[6],  (const float*)d_in[12]};
    const float* qkv_w[2] = {(const float*)d_in[7],  (const float*)d_in[13]};
    const float* out_w[2] = {(const float*)d_in[8],  (const float*)d_in[14]};
    const float* out_b[2] = {(const float*)d_in[9],  (const float*)d_in[15]};
    const float* res_w[2] = {(const float*)d_in[10], (const float*)d_in[16]};
    const float* pw7 = (const float*)d_in[17]; const float* pb7 = (const float*)d_in[18];
    const float* pw5 = (const float*)d_in[19]; const float* pb5 = (const float*)d_in[20];
    const float* pw3 = (const float*)d_in[21]; const float* pb3 = (const float*)d_in[22];
    const float* nf_g = (const float*)d_in[23]; const float* nf_b = (const float*)d_in[24];
    const float* fc2w = (const float*)d_in[25]; const float* fc2b = (const float*)d_in[26];

    float*  ws    = (float*)d_ws;
    float*  H     = ws + OFF_H;
    ushort* LNXb  = (ushort*)(ws + OFF_LNXO);
    float*  O     = ws + OFF_LNXO;
    ushort* QKVb  = (ushort*)(ws + OFF_QKVB);
    ushort* EOb   = (ushort*)(ws + OFF_QKVB);  // bf16 MoE expert out (pre-stage alias)
    float*  PBV   = ws + OFF_PBV;
    float*  PM    = ws + OFF_PM;
    float*  PL    = ws + OFF_PL;
    ushort* Ob    = (ushort*)(ws + OFF_OB);
    ushort* VT    = (ushort*)(ws + OFF_VT);
    ushort* QL    = (ushort*)(ws + OFF_QL);
    ushort* KL    = (ushort*)(ws + OFF_KL);
    float*  A2F   = ws + OFF_A2F;
    ushort* BVTb  = (ushort*)(ws + OFF_BVTB);
    ushort* Xb    = (ushort*)(ws + OFF_XB);
    ushort* XZB   = (ushort*)(ws + OFF_XZB);
    ushort* XZT7  = (ushort*)(ws + OFF_XZT7);
    ushort* PT15  = (ushort*)(ws + OFF_PT15);
    ushort* QT13  = (ushort*)(ws + OFF_QT13);
    ushort* ZB[2] = {(ushort*)(ws + OFF_ZB0), (ushort*)(ws + OFF_ZB1)};
    ushort* ZT[2] = {(ushort*)(ws + OFF_ZT0), (ushort*)(ws + OFF_ZT1)};
    ushort* ZBT   = (ushort*)(ws + OFF_ZBT);
    ushort* QWB   = (ushort*)(ws + OFF_QWB);
    ushort* OWB   = (ushort*)(ws + OFF_OWB);
    ushort* DATAB = (ushort*)(ws + OFF_DATAB);
    ushort* EWB   = (ushort*)(ws + OFF_EWB);
    float*  COLS  = ws + OFF_COLS;
    float*  SCAL  = ws + OFF_SCAL;

    const long long HSB = (long long)LMK * DHEAD;   // 65536
    const long long A2S = (long long)LMK * LMK;     // 262144

    // ---- MoE ----
    cvt_bf16<<<4500, 256, 0, stream>>>(data, DATAB, (long long)NTOK * INDIM);
    cvt_bf16<<<2304, 256, 0, stream>>>(expert_w, EWB, 3072LL * INDIM);
    mg<2><<<dim3(24,47,1),256,0,stream>>>(DATAB,INDIM,0, EWB,INDIM,0, EOb,3072,0,
        nullptr,0,0, NTOK,INDIM, nullptr, 1.f,0.f,0.f);
    moe_combine<<<NTOK,256,0,stream>>>(data, w_gate, EOb, expert_b, H);
    cls_copy<<<1,256,0,stream>>>(cls_tok, H);

    for (int stage = 0; stage < 2; stage++) {
        cvt_bf16<<<1536, 256, 0, stream>>>(qkv_w[stage], QWB, 3072LL * DIM);
        cvt_bf16<<<512, 256, 0, stream>>>(out_w[stage], OWB, (long long)DIM * DIM);
        ln_pad<<<NPL,256,0,stream>>>(H, ln_g[stage], ln_b[stage], LNXb);
        mg<1><<<dim3(24,48,1),256,0,stream>>>(LNXb,DIM,0, QWB,DIM,0, QKVb,3072,0,
            nullptr,0,0, NPL,DIM, nullptr, 1.f,0.f,0.f);
        landmarks<<<dim3(LMK,HEADS),128,0,stream>>>(QKVb, QL, KL);
        vtrans<<<dim3(192,4,8),dim3(32,8),0,stream>>>(QKVb, VT);
        // a2 = softmax(ql @ kl^T) f32
        mg<0><<<dim3(4,4,8),256,0,stream>>>(QL,DHEAD,HSB, KL,DHEAD,HSB, A2F,LMK,A2S,
            nullptr,0,0, LMK,DHEAD, nullptr, 1.f,0.f,0.f);
        softmax_rows<2><<<HEADS*LMK,256,0,stream>>>(A2F, LMK);
        hipMemsetAsync(COLS, 0, HEADS * LMK * sizeof(float), stream);
        a2_sums2<<<dim3(HEADS,8),256,0,stream>>>(A2F, COLS);
        a2_scal2<<<1,256,0,stream>>>(COLS, SCAL);
        z0_t<<<dim3(16,16,8),dim3(32,8),0,stream>>>(A2F, Xb, ZB[0], ZT[0], SCAL);
        // Newton-Schulz: 6 iterations, all bf16 MFMA
        int cur = 0;
        for (int it = 0; it < 6; it++) {
            mg<4><<<dim3(4,4,8),256,0,stream>>>(Xb,LMK,A2S, ZT[cur],LMK,A2S, XZB,LMK,A2S,
                XZT7,LMK,A2S, LMK,LMK, nullptr, 1.f, 7.f, -1.f);
            mg<5><<<dim3(4,4,8),256,0,stream>>>(XZB,LMK,A2S, XZT7,LMK,A2S, nullptr,0,0,
                PT15,LMK,A2S, LMK,LMK, nullptr, 1.f, 15.f, -1.f);
            mg<5><<<dim3(4,4,8),256,0,stream>>>(XZB,LMK,A2S, PT15,LMK,A2S, nullptr,0,0,
                QT13,LMK,A2S, LMK,LMK, nullptr, 1.f, 13.f, -1.f);
            if (it < 5)
                mg<4><<<dim3(4,4,8),256,0,stream>>>(ZB[cur],LMK,A2S, QT13,LMK,A2S, ZB[1-cur],LMK,A2S,
                    ZT[1-cur],LMK,A2S, LMK,LMK, nullptr, 0.25f, 0.f, 1.f);
            else
                mg<2><<<dim3(4,4,8),256,0,stream>>>(ZB[cur],LMK,A2S, QT13,LMK,A2S, ZB[1-cur],LMK,A2S,
                    nullptr,0,0, LMK,LMK, nullptr, 0.25f, 0.f, 1.f);
            cur = 1 - cur;
        }
        ushort* Z6 = ZB[cur];
        // flash a3: partial bv over 8 kv-chunks of 768
        flash<1><<<dim3(4,8,8),256,0,stream>>>(QL,DHEAD,HSB, QKVb+1024,3072,128,
            VT,NPL,(long long)DHEAD*NPL, PBV, PM, PL, 12, 768);
        bv_combine<<<dim3(16,8),256,0,stream>>>(PBV, PM, PL, BVTb);
        // ZBT[d][l'] = sum_l bvT[d][l] z6[l'][l]
        mg<2><<<dim3(4,1,8),256,0,stream>>>(BVTb,LMK,HSB, Z6,LMK,A2S, ZBT,LMK,HSB,
            nullptr,0,0, DHEAD,LMK, nullptr, 1.f,0.f,0.f);
        // flash a1: O = softmax(q @ kl^T) @ zb
        flash<0><<<dim3(48,1,8),256,0,stream>>>(QKVb,3072,128, KL,DHEAD,HSB,
            ZBT,LMK,HSB, O, nullptr, nullptr, 8, 0);
        // Ob = bf16(O + res conv of v)
        resconv<<<(NPL*DIM)/256,256,0,stream>>>(QKVb, res_w[stage], O, Ob);
        // H += Ob @ out_w^T + out_b
        mg<3><<<dim3(8,48,1),256,0,stream>>>(Ob + (long long)PAD*DIM,DIM,0, OWB,DIM,0, H,DIM,0,
            nullptr,0,0, NH,DIM, out_b[stage], 1.f,0.f,0.f);
        if (stage == 0) {
            float* F  = ws + OFF_QKVB;
            float* F2 = F + 6230016LL;
            h2f<<<dim3(191,32),dim3(32,8),0,stream>>>(H, F);
            ppeg_conv2<<<DIM,256,0,stream>>>(F, pw7, pb7, pw5, pb5, pw3, pb3, F2);
            f2h<<<dim3(32,191),dim3(32,8),0,stream>>>(F2, H);
        }
    }

    head_k<<<1,256,0,stream>>>(H, nf_g, nf_b, fc2w, fc2b, (float*)d_out);
}